// Round 19
// baseline (79.549 us; speedup 1.0000x reference)
//
#include <hip/hip_runtime.h>

// ---------------------------------------------------------------------------
// StickyHDPHMMVI emission log-likelihood, f16 MFMA + symmetry + mask-compact:
// out[bt,k] = c0_k - 0.5 * sum_x A[bt,x] * B[k,x]   (masked bt -> 0)
// x enumerates SYMMETRIC pair-blocks (bI<=bJ) of the 64x64 (d,e) space:
//   pair pb=(bI,bJ), chunks c = pb*2+p (p=0,1), slot s = g*8+q:
//     d = bI*8 + p*4 + g, e = bJ*8 + q
//     A = S0[d][e] (mu muT + F FT),  B = E_k[d][e] * (bI<bJ ? 2 : 1)
//   c=72,73: A = mu[t],  B = -2*v_k[t];  c=74,75: A = var[t], B = E_k[t,t]
// B lane-ordered: BG[((c*3 + j)*64 + kc*4 + g)*8 + q], k = j*16+kc
// k columns 0..31 via TWO MFMA; k=32 via 4x v_dot2 + shfl g-reduce (r18).
// r19: ~50% of bt are masked (output exactly 0). d_out is memset to 0; a
// compaction block (fused into prep grid as block 33) builds idx[] of active
// bt; main indirects staging/epilogue through idx and half its blocks exit
// after one load. Deterministic: mask is a fixed input.
// Refuted-null pile: addressing(r13), reg budget(r15), forced occupancy
// (r11 spill storm), L1 pairing(r16), LDS ring(r17). Work cuts always paid.
// ---------------------------------------------------------------------------

#define BT_TOTAL 32768
#define BT_BLK 16
#define NCHUNK 76

typedef _Float16 f16;
typedef __attribute__((ext_vector_type(8))) _Float16 f16x8;
typedef __attribute__((ext_vector_type(4))) _Float16 f16x4;
typedef __attribute__((ext_vector_type(2))) _Float16 h2;
typedef __attribute__((ext_vector_type(4))) float f32x4;
typedef struct { h2 p[4]; } h2q;

#if __has_builtin(__builtin_amdgcn_fdot2)
#define DOT2(a, b, c) __builtin_amdgcn_fdot2((a), (b), (c), false)
#else
#define DOT2(a, b, c) fmaf((float)(a)[0], (float)(b)[0], fmaf((float)(a)[1], (float)(b)[1], (c)))
#endif

// pair-block tables (bJ outer 0..7, bI inner 0..bJ), +1 guard entry
__constant__ unsigned char PB_BJ[37] =
  {0, 1,1, 2,2,2, 3,3,3,3, 4,4,4,4,4, 5,5,5,5,5,5, 6,6,6,6,6,6,6, 7,7,7,7,7,7,7,7, 7};
__constant__ unsigned char PB_BI[37] =
  {0, 0,1, 0,1,2, 0,1,2,3, 0,1,2,3,4, 0,1,2,3,4,5, 0,1,2,3,4,5,6, 0,1,2,3,4,5,6,7, 7};

__device__ __forceinline__ float digammaf_(float x){
  float r = 0.f;
  while (x < 6.f){ r -= 1.f / x; x += 1.f; }
  float xi = 1.f / x;
  float xi2 = xi * xi;
  return r + logf(x) - 0.5f * xi
         - xi2 * (0.083333333333f - xi2 * (0.0083333333333f - xi2 * 0.0039682539683f));
}

__device__ __forceinline__ float wsum64(float x){
  #pragma unroll
  for (int o = 32; o > 0; o >>= 1) x += __shfl_down(x, o);
  return x;  // valid in lane 0
}

// ---------- kernel A: per-k prep (blocks 0..32) + mask compact (block 33) ---
__global__ __launch_bounds__(256) void prep_kernel(
    const float* __restrict__ mu_k, const float* __restrict__ Psi,
    const float* __restrict__ nu_a, const float* __restrict__ kap_a,
    const unsigned char* __restrict__ maskb,
    f16* __restrict__ BG, float* __restrict__ c0o,
    int* __restrict__ nactp, int* __restrict__ idxb)
{
  const int tid = threadIdx.x;

  if (blockIdx.x == 33){
    // ---- mask compaction: idxb[] = active bt indices, *nactp = count ----
    __shared__ int cnts[256];
    const int l = tid & 63;
    const bool byteMask =
        __any((maskb[4 * l + 1] | maskb[4 * l + 2] | maskb[4 * l + 3]) != 0);
    const int base = tid * 128;
    int cnt = 0;
    for (int j = 0; j < 128; ++j){
      const int bt = base + j;
      const bool mk = byteMask ? (maskb[bt] != 0) : (maskb[(size_t)4 * bt] != 0);
      cnt += mk ? 1 : 0;
    }
    cnts[tid] = cnt;
    __syncthreads();
    // inclusive scan (Hillis-Steele)
    for (int off = 1; off < 256; off <<= 1){
      int v = cnts[tid];
      int u = (tid >= off) ? cnts[tid - off] : 0;
      __syncthreads();
      cnts[tid] = v + u;
      __syncthreads();
    }
    int wofs = cnts[tid] - cnt;          // exclusive
    for (int j = 0; j < 128; ++j){
      const int bt = base + j;
      const bool mk = byteMask ? (maskb[bt] != 0) : (maskb[(size_t)4 * bt] != 0);
      if (mk) idxb[wofs++] = bt;
    }
    if (tid == 255) *nactp = cnts[255];
    return;
  }

  const int k = blockIdx.x;
  const int row = tid & 63;
  const int ch  = tid >> 6;        // column chunk: cols [ch*32, ch*32+32) of 128
  const int c0  = ch << 5;

  __shared__ float pr[2][128];
  __shared__ float fc[2][64];
  __shared__ float diag[64];
  __shared__ float muk[64];
  __shared__ float vpart[2][64];
  __shared__ float Ediag[64];

  float Wr[32];
  if (ch < 2){
    const float* Pg = Psi + (size_t)k * 4096 + (size_t)row * 64 + c0;
    #pragma unroll
    for (int c = 0; c < 32; ++c) Wr[c] = Pg[c];
  } else {
    #pragma unroll
    for (int c = 0; c < 32; ++c) Wr[c] = ((c0 - 64 + c) == row) ? 1.f : 0.f;
  }
  if (tid < 64) muk[tid] = mu_k[k * 64 + tid];
  if (row == 0){
    #pragma unroll
    for (int c = 0; c < 32; ++c) pr[0][c0 + c] = Wr[c];
  }
  if (ch == 0) fc[0][row] = Wr[0];
  __syncthreads();

  for (int jh = 0; jh < 2; ++jh){
    #pragma unroll
    for (int jl = 0; jl < 32; ++jl){
      const int j = jh * 32 + jl;
      const int cur = j & 1, nxt = cur ^ 1;
      float piv = pr[cur][j];
      float f = fc[cur][row] * __builtin_amdgcn_rcpf(piv);
      if (row == j && ch == 0) diag[j] = piv;
      if (row != j){
        #pragma unroll
        for (int c = 0; c < 32; ++c) Wr[c] = fmaf(-f, pr[cur][c0 + c], Wr[c]);
      }
      if (j < 63){
        if (row == j + 1){
          #pragma unroll
          for (int c = 0; c < 32; ++c) pr[nxt][c0 + c] = Wr[c];
        }
        if (jl < 31){ if (ch == jh)     fc[nxt][row] = Wr[jl + 1]; }
        else        { if (ch == jh + 1) fc[nxt][row] = Wr[0]; }
      }
      __syncthreads();
    }
  }

  const float nu = nu_a[k];
  const int j_k = k >> 4, kck = k & 15;

  if (ch >= 2){
    const int h = ch - 2;                   // e-half this thread owns
    const float dinv = nu / diag[row];
    float vp = 0.f;
    #pragma unroll
    for (int c = 0; c < 32; ++c) vp = fmaf(Wr[c], muk[h * 32 + c], vp);
    vpart[h][row] = vp * dinv;
    // E-row scatter into symmetric pair-block layout (only bI <= bJ stored)
    const int d = row;
    const int bI = d >> 3;
    const int pch = (d >> 2) & 1;
    const int sHi = d & 3;                  // g-slot
    #pragma unroll
    for (int cc = 0; cc < 32; ++cc){
      const int e = h * 32 + cc;
      const int bJ = e >> 3;
      float val = Wr[cc] * dinv;
      if (e == d) Ediag[row] = val;
      if (bI <= bJ){
        const int pb = ((bJ * (bJ + 1)) >> 1) + bI;
        const int ci = pb * 2 + pch;
        const float sc = (bI < bJ) ? 2.f : 1.f;
        BG[(size_t)((ci * 3 + j_k) * 64 + kck * 4 + sHi) * 8 + (e & 7)] = (f16)(val * sc);
      }
    }
  }
  __syncthreads();

  if (tid < 64){
    const int t = tid;
    float v = vpart[0][t] + vpart[1][t];
    const int g = (t >> 3) & 3, q = t & 7;
    const int cA = 72 + (t >> 5);
    const int cB = 74 + (t >> 5);
    BG[(size_t)((cA * 3 + j_k) * 64 + kck * 4 + g) * 8 + q] = (f16)(-2.f * v);
    BG[(size_t)((cB * 3 + j_k) * 64 + kck * 4 + g) * 8 + q] = (f16)(Ediag[t]);
    float c2 = wsum64(v * muk[t]);
    float dg = wsum64(digammaf_((nu - (float)t) * 0.5f));
    float ld = wsum64(logf(diag[t]));
    if (t == 0){
      const float LN2   = 0.69314718055994531f;
      const float LN2PI = 1.83787706640934548f;
      float Elogdet = dg + 64.f * LN2 - ld;
      float cst = 0.5f * (Elogdet - 64.f * LN2PI);
      c0o[k] = cst - 0.5f * c2 - 32.f / kap_a[k];
    }
  }
}

// -------- kernel B: main (f16 MFMA x2 + k32 dot, compacted bt tiles) --------
#define BUILD(AF, FD, MUD)                                                 \
  {                                                                        \
    float s_[8];                                                           \
    _Pragma("unroll")                                                      \
    for (int q_ = 0; q_ < 8; ++q_) s_[q_] = (MUD) * mue[q_];               \
    _Pragma("unroll")                                                      \
    for (int r_ = 0; r_ < 4; ++r_){                                        \
      h2 fp_ = { (FD)[2 * r_], (FD)[2 * r_ + 1] };                         \
      _Pragma("unroll")                                                    \
      for (int q_ = 0; q_ < 8; ++q_){                                      \
        h2 ep_ = { FeT[q_][2 * r_], FeT[q_][2 * r_ + 1] };                 \
        s_[q_] = DOT2(fp_, ep_, s_[q_]);                                   \
      }                                                                    \
    }                                                                      \
    _Pragma("unroll")                                                      \
    for (int q_ = 0; q_ < 8; ++q_) (AF)[q_] = (f16)s_[q_];                 \
  }

#define MFMA2(AF, B0, B1)                                                  \
  acc0 = __builtin_amdgcn_mfma_f32_16x16x32_f16((AF), (B0), acc0, 0, 0, 0);\
  acc1 = __builtin_amdgcn_mfma_f32_16x16x32_f16((AF), (B1), acc1, 0, 0, 0);

#define K32DOT(AF, B32)                                                    \
  {                                                                        \
    h2q afq_ = __builtin_bit_cast(h2q, (AF));                              \
    h2q bq_  = __builtin_bit_cast(h2q, (B32));                             \
    _Pragma("unroll")                                                      \
    for (int r_ = 0; r_ < 4; ++r_)                                         \
      acc32 = DOT2(afq_.p[r_], bq_.p[r_], acc32);                          \
  }

__global__ __launch_bounds__(128) void main_kernel(
    const float* __restrict__ mu_t, const float* __restrict__ var_t,
    const float* __restrict__ F_t,
    const f16* __restrict__ BG, const float* __restrict__ c0o,
    const int* __restrict__ nactp, const int* __restrict__ idxb,
    float* __restrict__ out)
{
  __shared__ __align__(16) f16 sG[BT_BLK][64][8];  // F[d][r], d^(bt&7); 16384 B
  __shared__ __align__(16) f16 sMu[BT_BLK][64];    // block-8 d-swizzle;  2048 B
  __shared__ int sIdx[BT_BLK];
  __shared__ int sN;

  const int tid = threadIdx.x;
  const int l = tid & 63;
  const int xh = tid >> 6;               // wave = pair-range half
  const int g = l >> 4;
  const int kc = l & 15;
  const int btl = kc;                    // this lane's local A row
  const int btSw = btl & 7;

  const int nact = *nactp;
  const int t0 = blockIdx.x * BT_BLK;
  if (t0 >= nact) return;                // fully-masked tile: out already 0
  const int nLoc = min(BT_BLK, nact - t0);

  if (tid < BT_BLK)
    sIdx[tid] = idxb[t0 + min(tid, nLoc - 1)];   // clamp for partial tile
  if (tid == 0) sN = nLoc;
  __syncthreads();

  // ---- stage F / mu into LDS (coalesced per row, f32->f16, via idx) ----
  {
    #pragma unroll
    for (int ii = 0; ii < 16; ++ii){
      int i = tid + ii * 128;
      int bt = i >> 7, rem = i & 127, d = rem >> 1, rb = (rem & 1) << 2;
      const float4* fg = (const float4*)(F_t + (size_t)sIdx[bt] * 512);
      float4 f = fg[rem];
      int dsw = d ^ (bt & 7);
      f16x4 ff = { (f16)f.x, (f16)f.y, (f16)f.z, (f16)f.w };
      *(f16x4*)&sG[bt][dsw][rb] = ff;
    }
    #pragma unroll
    for (int ii = 0; ii < 2; ++ii){
      int i = tid + ii * 128;
      int bt = i >> 4, e4 = i & 15, d0 = e4 << 2;
      const float4* mg = (const float4*)(mu_t + (size_t)sIdx[bt] * 64);
      float4 m4 = mg[e4];
      int dsw = (((d0 >> 3) ^ (bt & 7)) << 3) | (d0 & 7);
      f16x4 mm = { (f16)m4.x, (f16)m4.y, (f16)m4.z, (f16)m4.w };
      *(f16x4*)&sMu[bt][dsw] = mm;
    }
  }
  __syncthreads();

  // per-wave pair range: wave0 = pairs [0,19), wave1 = pairs [19,36) + ext
  const int ppStart = xh ? 19 : 0;
  const int ppEnd   = xh ? 36 : 19;

  f32x4 acc0 = {0.f,0.f,0.f,0.f}, acc1 = {0.f,0.f,0.f,0.f};
  float acc32 = 0.f;

  f16x8 FeT[8];      // F rows e = bJ*8+q (reloaded per bJ)
  float mue[8];

  const f16* bp   = BG + (size_t)(ppStart * 2) * 1536 + (size_t)(kc * 4 + g) * 8;
  const f16* bp32 = BG + (size_t)(ppStart * 2) * 1536 + 1024 + (size_t)g * 8;

  // prologue: stage A = chunk 2*ppStart, stage B = chunk 2*ppStart+1
  const int bI0 = PB_BI[ppStart];
  f16x8 fdA = *(const f16x8*)&sG[btl][(bI0 * 8 + g) ^ btSw][0];
  f16x8 fdB = *(const f16x8*)&sG[btl][(bI0 * 8 + 4 + g) ^ btSw][0];
  float mudA = (float)sMu[btl][((bI0 ^ btSw) << 3) | g];
  float mudB = (float)sMu[btl][((bI0 ^ btSw) << 3) | (4 + g)];

  f16x8 a0 = *(const f16x8*)(bp);
  f16x8 a1 = *(const f16x8*)(bp + 512);
  f16x8 b0v = *(const f16x8*)(bp + 1536);
  f16x8 b1v = *(const f16x8*)(bp + 1536 + 512);
  f16x8 w0v = *(const f16x8*)(bp32);
  f16x8 w1v = *(const f16x8*)(bp32 + 1536);
  bp += 3072;
  bp32 += 3072;

  int curBJ = -1;
  for (int pp = ppStart; pp < ppEnd; ++pp){
    const int bJ = PB_BJ[pp];
    if (bJ != curBJ){
      curBJ = bJ;
      #pragma unroll
      for (int q = 0; q < 8; ++q)
        FeT[q] = *(const f16x8*)&sG[btl][((bJ << 3) + q) ^ btSw][0];
      f16x8 mr = *(const f16x8*)&sMu[btl][((bJ ^ btSw) << 3)];
      #pragma unroll
      for (int q = 0; q < 8; ++q) mue[q] = (float)mr[q];
    }
    const int bIn = PB_BI[pp + 1];
    // ---- even chunk (stage A), refill with next pair's p=0 ----
    {
      f16x8 af;
      BUILD(af, fdA, mudA);
      MFMA2(af, a0, a1);
      K32DOT(af, w0v);
      a0 = *(const f16x8*)(bp);
      a1 = *(const f16x8*)(bp + 512);
      w0v = *(const f16x8*)(bp32);
      fdA = *(const f16x8*)&sG[btl][(bIn * 8 + g) ^ btSw][0];
      mudA = (float)sMu[btl][((bIn ^ btSw) << 3) | g];
    }
    // ---- odd chunk (stage B), refill with next pair's p=1 ----
    {
      f16x8 af;
      BUILD(af, fdB, mudB);
      MFMA2(af, b0v, b1v);
      K32DOT(af, w1v);
      b0v = *(const f16x8*)(bp + 1536);
      b1v = *(const f16x8*)(bp + 1536 + 512);
      w1v = *(const f16x8*)(bp32 + 1536);
      fdB = *(const f16x8*)&sG[btl][(bIn * 8 + 4 + g) ^ btSw][0];
      mudB = (float)sMu[btl][((bIn ^ btSw) << 3) | (4 + g)];
    }
    bp += 3072;
    bp32 += 3072;
  }

  // ---- ext chunks (wave 1 only), ABSOLUTE addressing at chunk 72 ----
  if (xh == 1){
    const f16* bpe   = BG + (size_t)72 * 1536 + (size_t)(kc * 4 + g) * 8;
    const f16* bpe32 = BG + (size_t)72 * 1536 + 1024 + (size_t)g * 8;
    #pragma unroll
    for (int m = 0; m < 4; ++m){
      f16x8 af;
      if (m < 2){
        af = *(const f16x8*)&sMu[btl][(((m * 4 + g) ^ btSw) << 3)];
      } else {
        const float* vr = var_t + (size_t)sIdx[btl] * 64 + (m - 2) * 32 + g * 8;
        f32x4 va = *(const f32x4*)(vr);
        f32x4 vb = *(const f32x4*)(vr + 4);
        #pragma unroll
        for (int r = 0; r < 4; ++r){ af[r] = (f16)va[r]; af[4 + r] = (f16)vb[r]; }
      }
      f16x8 e0 = *(const f16x8*)(bpe);
      f16x8 e1 = *(const f16x8*)(bpe + 512);
      f16x8 e32 = *(const f16x8*)(bpe32);
      MFMA2(af, e0, e1);
      K32DOT(af, e32);
      bpe += 1536;
      bpe32 += 1536;
    }
  }

  // ---- cross-wave reduce (aliased into sG after barrier) ----
  __syncthreads();                         // all waves done reading sG/sMu
  float* sRedF = (float*)sG;               // [64][9] floats = 2304 B
  if (xh == 1){
    const int bofs = l * 9;
    #pragma unroll
    for (int r = 0; r < 4; ++r){
      sRedF[bofs + r]     = acc0[r];
      sRedF[bofs + 4 + r] = acc1[r];
    }
    sRedF[bofs + 8] = acc32;
  }
  __syncthreads();
  if (xh == 0){
    const int bofs = l * 9;
    #pragma unroll
    for (int r = 0; r < 4; ++r){
      acc0[r] += sRedF[bofs + r];
      acc1[r] += sRedF[bofs + 4 + r];
    }
    acc32 += sRedF[bofs + 8];
    // g-reduce k32 (lanes same kc, different g)
    acc32 += __shfl_xor(acc32, 16);
    acc32 += __shfl_xor(acc32, 32);

    float c0a = c0o[kc];
    float c0b = c0o[16 + kc];
    float c0c = c0o[32];
    const int nLocR = sN;
    #pragma unroll
    for (int reg = 0; reg < 4; ++reg){
      int r16 = g * 4 + reg;
      if (r16 < nLocR){
        float* op = out + (size_t)sIdx[r16] * 33;
        op[kc]      = fmaf(-0.5f, acc0[reg], c0a);
        op[16 + kc] = fmaf(-0.5f, acc1[reg], c0b);
      }
    }
    if (g == 0 && kc < nLocR){
      out[(size_t)sIdx[kc] * 33 + 32] = fmaf(-0.5f, acc32, c0c);
    }
  }
}

// --------------------------- launch -----------------------------------------
extern "C" void kernel_launch(void* const* d_in, const int* in_sizes, int n_in,
                              void* d_out, int out_size, void* d_ws, size_t ws_size,
                              hipStream_t stream)
{
  const float* mu_t  = (const float*)d_in[0];
  const float* var_t = (const float*)d_in[1];
  const float* F_t   = (const float*)d_in[2];
  const float* mu_k  = (const float*)d_in[3];
  const float* Psi   = (const float*)d_in[4];
  const float* nu    = (const float*)d_in[5];
  const float* kap   = (const float*)d_in[6];
  const unsigned char* mask = (const unsigned char*)d_in[7];

  f16*   BG   = (f16*)d_ws;                             // 233472 B
  float* c0o  = (float*)((char*)d_ws + 233472);         // 132 B
  int*   nact = (int*)((char*)d_ws + 233472 + 256);     // 4 B
  int*   idxb = nact + 1;                               // 131072 B
  float* outp = (float*)d_out;

  (void)hipMemsetAsync(d_out, 0, (size_t)out_size * 4, stream);
  hipLaunchKernelGGL(prep_kernel, dim3(34), dim3(256), 0, stream,
                     mu_k, Psi, nu, kap, mask, BG, c0o, nact, idxb);
  hipLaunchKernelGGL(main_kernel, dim3(BT_TOTAL / BT_BLK), dim3(128), 0, stream,
                     mu_t, var_t, F_t, BG, c0o, nact, idxb, outp);
}

// Round 20
// 70.002 us; speedup vs baseline: 1.1364x; 1.1364x over previous
//
#include <hip/hip_runtime.h>

// ---------------------------------------------------------------------------
// StickyHDPHMMVI emission log-likelihood, f16 MFMA + symmetry + mask-compact:
// out[bt,k] = c0_k - 0.5 * sum_x A[bt,x] * B[k,x]   (masked bt -> 0)
// x enumerates SYMMETRIC pair-blocks (bI<=bJ) of the 64x64 (d,e) space:
//   pair pb=(bI,bJ), chunks c = pb*2+p (p=0,1), slot s = g*8+q:
//     d = bI*8 + p*4 + g, e = bJ*8 + q
//     A = S0[d][e] (mu muT + F FT),  B = E_k[d][e] * (bI<bJ ? 2 : 1)
//   c=72,73: A = mu[t],  B = -2*v_k[t];  c=74,75: A = var[t], B = E_k[t,t]
// B lane-ordered: BG[((c*3 + j)*64 + kc*4 + g)*8 + q], k = j*16+kc
// k columns 0..31 via TWO MFMA; k=32 via 4x v_dot2 + shfl g-reduce (r18).
// Mask compaction (prep block 33) r20: VECTORIZED uint4 loads (r19's scalar
// byte loops were the 44us straggler — 256 latency-bound loads/thread).
// Refuted-null pile: addressing(r13), reg budget(r15), forced occupancy
// (r11 spill storm), L1 pairing(r16), LDS ring(r17). Work cuts always paid.
// ---------------------------------------------------------------------------

#define BT_TOTAL 32768
#define BT_BLK 16
#define NCHUNK 76

typedef _Float16 f16;
typedef __attribute__((ext_vector_type(8))) _Float16 f16x8;
typedef __attribute__((ext_vector_type(4))) _Float16 f16x4;
typedef __attribute__((ext_vector_type(2))) _Float16 h2;
typedef __attribute__((ext_vector_type(4))) float f32x4;
typedef struct { h2 p[4]; } h2q;

#if __has_builtin(__builtin_amdgcn_fdot2)
#define DOT2(a, b, c) __builtin_amdgcn_fdot2((a), (b), (c), false)
#else
#define DOT2(a, b, c) fmaf((float)(a)[0], (float)(b)[0], fmaf((float)(a)[1], (float)(b)[1], (c)))
#endif

// pair-block tables (bJ outer 0..7, bI inner 0..bJ), +1 guard entry
__constant__ unsigned char PB_BJ[37] =
  {0, 1,1, 2,2,2, 3,3,3,3, 4,4,4,4,4, 5,5,5,5,5,5, 6,6,6,6,6,6,6, 7,7,7,7,7,7,7,7, 7};
__constant__ unsigned char PB_BI[37] =
  {0, 0,1, 0,1,2, 0,1,2,3, 0,1,2,3,4, 0,1,2,3,4,5, 0,1,2,3,4,5,6, 0,1,2,3,4,5,6,7, 7};

__device__ __forceinline__ float digammaf_(float x){
  float r = 0.f;
  while (x < 6.f){ r -= 1.f / x; x += 1.f; }
  float xi = 1.f / x;
  float xi2 = xi * xi;
  return r + logf(x) - 0.5f * xi
         - xi2 * (0.083333333333f - xi2 * (0.0083333333333f - xi2 * 0.0039682539683f));
}

__device__ __forceinline__ float wsum64(float x){
  #pragma unroll
  for (int o = 32; o > 0; o >>= 1) x += __shfl_down(x, o);
  return x;  // valid in lane 0
}

// ---------- kernel A: per-k prep (blocks 0..32) + mask compact (block 33) ---
__global__ __launch_bounds__(256) void prep_kernel(
    const float* __restrict__ mu_k, const float* __restrict__ Psi,
    const float* __restrict__ nu_a, const float* __restrict__ kap_a,
    const unsigned char* __restrict__ maskb,
    f16* __restrict__ BG, float* __restrict__ c0o,
    int* __restrict__ nactp, int* __restrict__ idxb)
{
  const int tid = threadIdx.x;

  if (blockIdx.x == 33){
    // ---- mask compaction (vectorized): idxb[] = active bt, *nactp = count --
    __shared__ int cnts[256];
    const int l = tid & 63;
    const bool byteMask =
        __any((maskb[4 * l + 1] | maskb[4 * l + 2] | maskb[4 * l + 3]) != 0);
    // flags for bt in [tid*128, tid*128+128), packed 4 per uint32 word
    unsigned int fl[32];            // fl[j] bits: word with 4 flag bytes
    if (byteMask){
      const uint4* mv = (const uint4*)(maskb + (size_t)tid * 128);
      #pragma unroll
      for (int j = 0; j < 8; ++j){
        uint4 v = mv[j];
        fl[4 * j + 0] = v.x; fl[4 * j + 1] = v.y;
        fl[4 * j + 2] = v.z; fl[4 * j + 3] = v.w;
      }
      // count nonzero bytes
      int cnt = 0;
      #pragma unroll
      for (int j = 0; j < 32; ++j){
        unsigned int w = fl[j];
        cnt += ((w & 0xFFu) != 0) + ((w & 0xFF00u) != 0)
             + ((w & 0xFF0000u) != 0) + ((w & 0xFF000000u) != 0);
      }
      cnts[tid] = cnt;
      __syncthreads();
      for (int off = 1; off < 256; off <<= 1){
        int v = cnts[tid];
        int u = (tid >= off) ? cnts[tid - off] : 0;
        __syncthreads();
        cnts[tid] = v + u;
        __syncthreads();
      }
      int wofs = cnts[tid] - cnts[tid] + (cnts[tid] - ((tid > 0) ? 0 : 0));
      wofs = cnts[tid];
      // recompute exclusive
      {
        int cnt2 = 0;
        #pragma unroll
        for (int j = 0; j < 32; ++j){
          unsigned int w = fl[j];
          cnt2 += ((w & 0xFFu) != 0) + ((w & 0xFF00u) != 0)
                + ((w & 0xFF0000u) != 0) + ((w & 0xFF000000u) != 0);
        }
        wofs = cnts[tid] - cnt2;
      }
      const int base = tid * 128;
      #pragma unroll
      for (int j = 0; j < 32; ++j){
        unsigned int w = fl[j];
        if (w & 0xFFu)       idxb[wofs++] = base + 4 * j + 0;
        if (w & 0xFF00u)     idxb[wofs++] = base + 4 * j + 1;
        if (w & 0xFF0000u)   idxb[wofs++] = base + 4 * j + 2;
        if (w & 0xFF000000u) idxb[wofs++] = base + 4 * j + 3;
      }
      if (tid == 255) *nactp = cnts[255];
    } else {
      // int32 flags: 128 words = 32 uint4 per thread
      const uint4* mv = (const uint4*)maskb + (size_t)tid * 32;
      unsigned int nz[32];          // bit s of nz[j] = flag of word 4j+s
      int cnt = 0;
      #pragma unroll
      for (int j = 0; j < 32; ++j){
        uint4 v = mv[j];
        unsigned int b = (v.x != 0) | ((v.y != 0) << 1)
                       | ((v.z != 0) << 2) | ((v.w != 0) << 3);
        nz[j] = b;
        cnt += __popc(b);
      }
      cnts[tid] = cnt;
      __syncthreads();
      for (int off = 1; off < 256; off <<= 1){
        int v = cnts[tid];
        int u = (tid >= off) ? cnts[tid - off] : 0;
        __syncthreads();
        cnts[tid] = v + u;
        __syncthreads();
      }
      int wofs = cnts[tid] - cnt;
      const int base = tid * 128;
      #pragma unroll
      for (int j = 0; j < 32; ++j){
        unsigned int b = nz[j];
        if (b & 1u) idxb[wofs++] = base + 4 * j + 0;
        if (b & 2u) idxb[wofs++] = base + 4 * j + 1;
        if (b & 4u) idxb[wofs++] = base + 4 * j + 2;
        if (b & 8u) idxb[wofs++] = base + 4 * j + 3;
      }
      if (tid == 255) *nactp = cnts[255];
    }
    return;
  }

  const int k = blockIdx.x;
  const int row = tid & 63;
  const int ch  = tid >> 6;        // column chunk: cols [ch*32, ch*32+32) of 128
  const int c0  = ch << 5;

  __shared__ float pr[2][128];
  __shared__ float fc[2][64];
  __shared__ float diag[64];
  __shared__ float muk[64];
  __shared__ float vpart[2][64];
  __shared__ float Ediag[64];

  float Wr[32];
  if (ch < 2){
    const float* Pg = Psi + (size_t)k * 4096 + (size_t)row * 64 + c0;
    #pragma unroll
    for (int c = 0; c < 32; ++c) Wr[c] = Pg[c];
  } else {
    #pragma unroll
    for (int c = 0; c < 32; ++c) Wr[c] = ((c0 - 64 + c) == row) ? 1.f : 0.f;
  }
  if (tid < 64) muk[tid] = mu_k[k * 64 + tid];
  if (row == 0){
    #pragma unroll
    for (int c = 0; c < 32; ++c) pr[0][c0 + c] = Wr[c];
  }
  if (ch == 0) fc[0][row] = Wr[0];
  __syncthreads();

  for (int jh = 0; jh < 2; ++jh){
    #pragma unroll
    for (int jl = 0; jl < 32; ++jl){
      const int j = jh * 32 + jl;
      const int cur = j & 1, nxt = cur ^ 1;
      float piv = pr[cur][j];
      float f = fc[cur][row] * __builtin_amdgcn_rcpf(piv);
      if (row == j && ch == 0) diag[j] = piv;
      if (row != j){
        #pragma unroll
        for (int c = 0; c < 32; ++c) Wr[c] = fmaf(-f, pr[cur][c0 + c], Wr[c]);
      }
      if (j < 63){
        if (row == j + 1){
          #pragma unroll
          for (int c = 0; c < 32; ++c) pr[nxt][c0 + c] = Wr[c];
        }
        if (jl < 31){ if (ch == jh)     fc[nxt][row] = Wr[jl + 1]; }
        else        { if (ch == jh + 1) fc[nxt][row] = Wr[0]; }
      }
      __syncthreads();
    }
  }

  const float nu = nu_a[k];
  const int j_k = k >> 4, kck = k & 15;

  if (ch >= 2){
    const int h = ch - 2;                   // e-half this thread owns
    const float dinv = nu / diag[row];
    float vp = 0.f;
    #pragma unroll
    for (int c = 0; c < 32; ++c) vp = fmaf(Wr[c], muk[h * 32 + c], vp);
    vpart[h][row] = vp * dinv;
    // E-row scatter into symmetric pair-block layout (only bI <= bJ stored)
    const int d = row;
    const int bI = d >> 3;
    const int pch = (d >> 2) & 1;
    const int sHi = d & 3;                  // g-slot
    #pragma unroll
    for (int cc = 0; cc < 32; ++cc){
      const int e = h * 32 + cc;
      const int bJ = e >> 3;
      float val = Wr[cc] * dinv;
      if (e == d) Ediag[row] = val;
      if (bI <= bJ){
        const int pb = ((bJ * (bJ + 1)) >> 1) + bI;
        const int ci = pb * 2 + pch;
        const float sc = (bI < bJ) ? 2.f : 1.f;
        BG[(size_t)((ci * 3 + j_k) * 64 + kck * 4 + sHi) * 8 + (e & 7)] = (f16)(val * sc);
      }
    }
  }
  __syncthreads();

  if (tid < 64){
    const int t = tid;
    float v = vpart[0][t] + vpart[1][t];
    const int g = (t >> 3) & 3, q = t & 7;
    const int cA = 72 + (t >> 5);
    const int cB = 74 + (t >> 5);
    BG[(size_t)((cA * 3 + j_k) * 64 + kck * 4 + g) * 8 + q] = (f16)(-2.f * v);
    BG[(size_t)((cB * 3 + j_k) * 64 + kck * 4 + g) * 8 + q] = (f16)(Ediag[t]);
    float c2 = wsum64(v * muk[t]);
    float dg = wsum64(digammaf_((nu - (float)t) * 0.5f));
    float ld = wsum64(logf(diag[t]));
    if (t == 0){
      const float LN2   = 0.69314718055994531f;
      const float LN2PI = 1.83787706640934548f;
      float Elogdet = dg + 64.f * LN2 - ld;
      float cst = 0.5f * (Elogdet - 64.f * LN2PI);
      c0o[k] = cst - 0.5f * c2 - 32.f / kap_a[k];
    }
  }
}

// -------- kernel B: main (f16 MFMA x2 + k32 dot, compacted bt tiles) --------
#define BUILD(AF, FD, MUD)                                                 \
  {                                                                        \
    float s_[8];                                                           \
    _Pragma("unroll")                                                      \
    for (int q_ = 0; q_ < 8; ++q_) s_[q_] = (MUD) * mue[q_];               \
    _Pragma("unroll")                                                      \
    for (int r_ = 0; r_ < 4; ++r_){                                        \
      h2 fp_ = { (FD)[2 * r_], (FD)[2 * r_ + 1] };                         \
      _Pragma("unroll")                                                    \
      for (int q_ = 0; q_ < 8; ++q_){                                      \
        h2 ep_ = { FeT[q_][2 * r_], FeT[q_][2 * r_ + 1] };                 \
        s_[q_] = DOT2(fp_, ep_, s_[q_]);                                   \
      }                                                                    \
    }                                                                      \
    _Pragma("unroll")                                                      \
    for (int q_ = 0; q_ < 8; ++q_) (AF)[q_] = (f16)s_[q_];                 \
  }

#define MFMA2(AF, B0, B1)                                                  \
  acc0 = __builtin_amdgcn_mfma_f32_16x16x32_f16((AF), (B0), acc0, 0, 0, 0);\
  acc1 = __builtin_amdgcn_mfma_f32_16x16x32_f16((AF), (B1), acc1, 0, 0, 0);

#define K32DOT(AF, B32)                                                    \
  {                                                                        \
    h2q afq_ = __builtin_bit_cast(h2q, (AF));                              \
    h2q bq_  = __builtin_bit_cast(h2q, (B32));                             \
    _Pragma("unroll")                                                      \
    for (int r_ = 0; r_ < 4; ++r_)                                         \
      acc32 = DOT2(afq_.p[r_], bq_.p[r_], acc32);                          \
  }

__global__ __launch_bounds__(128) void main_kernel(
    const float* __restrict__ mu_t, const float* __restrict__ var_t,
    const float* __restrict__ F_t,
    const f16* __restrict__ BG, const float* __restrict__ c0o,
    const int* __restrict__ nactp, const int* __restrict__ idxb,
    float* __restrict__ out)
{
  __shared__ __align__(16) f16 sG[BT_BLK][64][8];  // F[d][r], d^(bt&7); 16384 B
  __shared__ __align__(16) f16 sMu[BT_BLK][64];    // block-8 d-swizzle;  2048 B
  __shared__ int sIdx[BT_BLK];
  __shared__ int sN;

  const int tid = threadIdx.x;
  const int l = tid & 63;
  const int xh = tid >> 6;               // wave = pair-range half
  const int g = l >> 4;
  const int kc = l & 15;
  const int btl = kc;                    // this lane's local A row
  const int btSw = btl & 7;

  const int nact = *nactp;
  const int t0 = blockIdx.x * BT_BLK;
  if (t0 >= nact) return;                // fully-masked tile: out already 0
  const int nLoc = min(BT_BLK, nact - t0);

  if (tid < BT_BLK)
    sIdx[tid] = idxb[t0 + min(tid, nLoc - 1)];   // clamp for partial tile
  if (tid == 0) sN = nLoc;
  __syncthreads();

  // ---- stage F / mu into LDS (coalesced per row, f32->f16, via idx) ----
  {
    #pragma unroll
    for (int ii = 0; ii < 16; ++ii){
      int i = tid + ii * 128;
      int bt = i >> 7, rem = i & 127, d = rem >> 1, rb = (rem & 1) << 2;
      const float4* fg = (const float4*)(F_t + (size_t)sIdx[bt] * 512);
      float4 f = fg[rem];
      int dsw = d ^ (bt & 7);
      f16x4 ff = { (f16)f.x, (f16)f.y, (f16)f.z, (f16)f.w };
      *(f16x4*)&sG[bt][dsw][rb] = ff;
    }
    #pragma unroll
    for (int ii = 0; ii < 2; ++ii){
      int i = tid + ii * 128;
      int bt = i >> 4, e4 = i & 15, d0 = e4 << 2;
      const float4* mg = (const float4*)(mu_t + (size_t)sIdx[bt] * 64);
      float4 m4 = mg[e4];
      int dsw = (((d0 >> 3) ^ (bt & 7)) << 3) | (d0 & 7);
      f16x4 mm = { (f16)m4.x, (f16)m4.y, (f16)m4.z, (f16)m4.w };
      *(f16x4*)&sMu[bt][dsw] = mm;
    }
  }
  __syncthreads();

  // per-wave pair range: wave0 = pairs [0,19), wave1 = pairs [19,36) + ext
  const int ppStart = xh ? 19 : 0;
  const int ppEnd   = xh ? 36 : 19;

  f32x4 acc0 = {0.f,0.f,0.f,0.f}, acc1 = {0.f,0.f,0.f,0.f};
  float acc32 = 0.f;

  f16x8 FeT[8];      // F rows e = bJ*8+q (reloaded per bJ)
  float mue[8];

  const f16* bp   = BG + (size_t)(ppStart * 2) * 1536 + (size_t)(kc * 4 + g) * 8;
  const f16* bp32 = BG + (size_t)(ppStart * 2) * 1536 + 1024 + (size_t)g * 8;

  // prologue: stage A = chunk 2*ppStart, stage B = chunk 2*ppStart+1
  const int bI0 = PB_BI[ppStart];
  f16x8 fdA = *(const f16x8*)&sG[btl][(bI0 * 8 + g) ^ btSw][0];
  f16x8 fdB = *(const f16x8*)&sG[btl][(bI0 * 8 + 4 + g) ^ btSw][0];
  float mudA = (float)sMu[btl][((bI0 ^ btSw) << 3) | g];
  float mudB = (float)sMu[btl][((bI0 ^ btSw) << 3) | (4 + g)];

  f16x8 a0 = *(const f16x8*)(bp);
  f16x8 a1 = *(const f16x8*)(bp + 512);
  f16x8 b0v = *(const f16x8*)(bp + 1536);
  f16x8 b1v = *(const f16x8*)(bp + 1536 + 512);
  f16x8 w0v = *(const f16x8*)(bp32);
  f16x8 w1v = *(const f16x8*)(bp32 + 1536);
  bp += 3072;
  bp32 += 3072;

  int curBJ = -1;
  for (int pp = ppStart; pp < ppEnd; ++pp){
    const int bJ = PB_BJ[pp];
    if (bJ != curBJ){
      curBJ = bJ;
      #pragma unroll
      for (int q = 0; q < 8; ++q)
        FeT[q] = *(const f16x8*)&sG[btl][((bJ << 3) + q) ^ btSw][0];
      f16x8 mr = *(const f16x8*)&sMu[btl][((bJ ^ btSw) << 3)];
      #pragma unroll
      for (int q = 0; q < 8; ++q) mue[q] = (float)mr[q];
    }
    const int bIn = PB_BI[pp + 1];
    // ---- even chunk (stage A), refill with next pair's p=0 ----
    {
      f16x8 af;
      BUILD(af, fdA, mudA);
      MFMA2(af, a0, a1);
      K32DOT(af, w0v);
      a0 = *(const f16x8*)(bp);
      a1 = *(const f16x8*)(bp + 512);
      w0v = *(const f16x8*)(bp32);
      fdA = *(const f16x8*)&sG[btl][(bIn * 8 + g) ^ btSw][0];
      mudA = (float)sMu[btl][((bIn ^ btSw) << 3) | g];
    }
    // ---- odd chunk (stage B), refill with next pair's p=1 ----
    {
      f16x8 af;
      BUILD(af, fdB, mudB);
      MFMA2(af, b0v, b1v);
      K32DOT(af, w1v);
      b0v = *(const f16x8*)(bp + 1536);
      b1v = *(const f16x8*)(bp + 1536 + 512);
      w1v = *(const f16x8*)(bp32 + 1536);
      fdB = *(const f16x8*)&sG[btl][(bIn * 8 + 4 + g) ^ btSw][0];
      mudB = (float)sMu[btl][((bIn ^ btSw) << 3) | (4 + g)];
    }
    bp += 3072;
    bp32 += 3072;
  }

  // ---- ext chunks (wave 1 only), ABSOLUTE addressing at chunk 72 ----
  if (xh == 1){
    const f16* bpe   = BG + (size_t)72 * 1536 + (size_t)(kc * 4 + g) * 8;
    const f16* bpe32 = BG + (size_t)72 * 1536 + 1024 + (size_t)g * 8;
    #pragma unroll
    for (int m = 0; m < 4; ++m){
      f16x8 af;
      if (m < 2){
        af = *(const f16x8*)&sMu[btl][(((m * 4 + g) ^ btSw) << 3)];
      } else {
        const float* vr = var_t + (size_t)sIdx[btl] * 64 + (m - 2) * 32 + g * 8;
        f32x4 va = *(const f32x4*)(vr);
        f32x4 vb = *(const f32x4*)(vr + 4);
        #pragma unroll
        for (int r = 0; r < 4; ++r){ af[r] = (f16)va[r]; af[4 + r] = (f16)vb[r]; }
      }
      f16x8 e0 = *(const f16x8*)(bpe);
      f16x8 e1 = *(const f16x8*)(bpe + 512);
      f16x8 e32 = *(const f16x8*)(bpe32);
      MFMA2(af, e0, e1);
      K32DOT(af, e32);
      bpe += 1536;
      bpe32 += 1536;
    }
  }

  // ---- cross-wave reduce (aliased into sG after barrier) ----
  __syncthreads();                         // all waves done reading sG/sMu
  float* sRedF = (float*)sG;               // [64][9] floats = 2304 B
  if (xh == 1){
    const int bofs = l * 9;
    #pragma unroll
    for (int r = 0; r < 4; ++r){
      sRedF[bofs + r]     = acc0[r];
      sRedF[bofs + 4 + r] = acc1[r];
    }
    sRedF[bofs + 8] = acc32;
  }
  __syncthreads();
  if (xh == 0){
    const int bofs = l * 9;
    #pragma unroll
    for (int r = 0; r < 4; ++r){
      acc0[r] += sRedF[bofs + r];
      acc1[r] += sRedF[bofs + 4 + r];
    }
    acc32 += sRedF[bofs + 8];
    // g-reduce k32 (lanes same kc, different g)
    acc32 += __shfl_xor(acc32, 16);
    acc32 += __shfl_xor(acc32, 32);

    float c0a = c0o[kc];
    float c0b = c0o[16 + kc];
    float c0c = c0o[32];
    const int nLocR = sN;
    #pragma unroll
    for (int reg = 0; reg < 4; ++reg){
      int r16 = g * 4 + reg;
      if (r16 < nLocR){
        float* op = out + (size_t)sIdx[r16] * 33;
        op[kc]      = fmaf(-0.5f, acc0[reg], c0a);
        op[16 + kc] = fmaf(-0.5f, acc1[reg], c0b);
      }
    }
    if (g == 0 && kc < nLocR){
      out[(size_t)sIdx[kc] * 33 + 32] = fmaf(-0.5f, acc32, c0c);
    }
  }
}

// --------------------------- launch -----------------------------------------
extern "C" void kernel_launch(void* const* d_in, const int* in_sizes, int n_in,
                              void* d_out, int out_size, void* d_ws, size_t ws_size,
                              hipStream_t stream)
{
  const float* mu_t  = (const float*)d_in[0];
  const float* var_t = (const float*)d_in[1];
  const float* F_t   = (const float*)d_in[2];
  const float* mu_k  = (const float*)d_in[3];
  const float* Psi   = (const float*)d_in[4];
  const float* nu    = (const float*)d_in[5];
  const float* kap   = (const float*)d_in[6];
  const unsigned char* mask = (const unsigned char*)d_in[7];

  f16*   BG   = (f16*)d_ws;                             // 233472 B
  float* c0o  = (float*)((char*)d_ws + 233472);         // 132 B
  int*   nact = (int*)((char*)d_ws + 233472 + 256);     // 4 B
  int*   idxb = nact + 1;                               // 131072 B
  float* outp = (float*)d_out;

  (void)hipMemsetAsync(d_out, 0, (size_t)out_size * 4, stream);
  hipLaunchKernelGGL(prep_kernel, dim3(34), dim3(256), 0, stream,
                     mu_k, Psi, nu, kap, mask, BG, c0o, nact, idxb);
  hipLaunchKernelGGL(main_kernel, dim3(BT_TOTAL / BT_BLK), dim3(128), 0, stream,
                     mu_t, var_t, F_t, BG, c0o, nact, idxb, outp);
}

// Round 21
// 66.838 us; speedup vs baseline: 1.1902x; 1.0473x over previous
//
#include <hip/hip_runtime.h>

// ---------------------------------------------------------------------------
// StickyHDPHMMVI emission log-likelihood, f16 MFMA + symmetry + mask-compact:
// out[bt,k] = c0_k - 0.5 * sum_x A[bt,x] * B[k,x]   (masked bt -> 0)
// x enumerates SYMMETRIC pair-blocks (bI<=bJ) of the 64x64 (d,e) space:
//   pair pb=(bI,bJ), chunks c = pb*2+p (p=0,1), slot s = g*8+q:
//     d = bI*8 + p*4 + g, e = bJ*8 + q
//     A = S0[d][e] (mu muT + F FT),  B = E_k[d][e] * (bI<bJ ? 2 : 1)
//   c=72,73: A = mu[t],  B = -2*v_k[t];  c=74,75: A = var[t], B = E_k[t,t]
// B lane-ordered: BG[((c*3 + j)*64 + kc*4 + g)*8 + q], k = j*16+kc
// k columns 0..31 via TWO MFMA; k=32 via 4x v_dot2 + shfl g-reduce (r18).
// r21: NO memset (r20's hipMemsetAsync ran 40us in the runtime's tiny-grid
// fill kernel — the top dispatch). Compaction emits a FULL permutation:
// idxb[0..nact) active, idxb[nact..32768) inactive. Main's 2048 blocks cover
// the whole list: inactive tiles write 33 zeros/row and exit; the straddle
// tile computes nLoc rows and zero-fills the rest. Every row written every
// launch (poison-safe, deterministic).
// Refuted-null pile: addressing(r13), reg budget(r15), forced occupancy
// (r11 spill storm), L1 pairing(r16), LDS ring(r17). Work cuts always paid.
// ---------------------------------------------------------------------------

#define BT_TOTAL 32768
#define BT_BLK 16
#define NCHUNK 76

typedef _Float16 f16;
typedef __attribute__((ext_vector_type(8))) _Float16 f16x8;
typedef __attribute__((ext_vector_type(4))) _Float16 f16x4;
typedef __attribute__((ext_vector_type(2))) _Float16 h2;
typedef __attribute__((ext_vector_type(4))) float f32x4;
typedef struct { h2 p[4]; } h2q;

#if __has_builtin(__builtin_amdgcn_fdot2)
#define DOT2(a, b, c) __builtin_amdgcn_fdot2((a), (b), (c), false)
#else
#define DOT2(a, b, c) fmaf((float)(a)[0], (float)(b)[0], fmaf((float)(a)[1], (float)(b)[1], (c)))
#endif

// pair-block tables (bJ outer 0..7, bI inner 0..bJ), +1 guard entry
__constant__ unsigned char PB_BJ[37] =
  {0, 1,1, 2,2,2, 3,3,3,3, 4,4,4,4,4, 5,5,5,5,5,5, 6,6,6,6,6,6,6, 7,7,7,7,7,7,7,7, 7};
__constant__ unsigned char PB_BI[37] =
  {0, 0,1, 0,1,2, 0,1,2,3, 0,1,2,3,4, 0,1,2,3,4,5, 0,1,2,3,4,5,6, 0,1,2,3,4,5,6,7, 7};

__device__ __forceinline__ float digammaf_(float x){
  float r = 0.f;
  while (x < 6.f){ r -= 1.f / x; x += 1.f; }
  float xi = 1.f / x;
  float xi2 = xi * xi;
  return r + logf(x) - 0.5f * xi
         - xi2 * (0.083333333333f - xi2 * (0.0083333333333f - xi2 * 0.0039682539683f));
}

__device__ __forceinline__ float wsum64(float x){
  #pragma unroll
  for (int o = 32; o > 0; o >>= 1) x += __shfl_down(x, o);
  return x;  // valid in lane 0
}

// ---------- kernel A: per-k prep (blocks 0..32) + mask compact (block 33) ---
__global__ __launch_bounds__(256) void prep_kernel(
    const float* __restrict__ mu_k, const float* __restrict__ Psi,
    const float* __restrict__ nu_a, const float* __restrict__ kap_a,
    const unsigned char* __restrict__ maskb,
    f16* __restrict__ BG, float* __restrict__ c0o,
    int* __restrict__ nactp, int* __restrict__ idxb)
{
  const int tid = threadIdx.x;

  if (blockIdx.x == 33){
    // ---- mask compaction: full permutation (active then inactive) ----
    __shared__ int cnts[256];
    const int l = tid & 63;
    const bool byteMask =
        __any((maskb[4 * l + 1] | maskb[4 * l + 2] | maskb[4 * l + 3]) != 0);
    unsigned int nz[32];            // bit s of nz[j] = flag of bt 4j+s
    int cnt = 0;
    if (byteMask){
      const uint4* mv = (const uint4*)(maskb + (size_t)tid * 128);
      #pragma unroll
      for (int j = 0; j < 8; ++j){
        uint4 v = mv[j];
        unsigned int w0 = v.x, w1 = v.y, w2 = v.z, w3 = v.w;
        unsigned int b0 = ((w0 & 0xFFu) != 0) | (((w0 & 0xFF00u) != 0) << 1)
                        | (((w0 & 0xFF0000u) != 0) << 2) | (((w0 & 0xFF000000u) != 0) << 3);
        unsigned int b1 = ((w1 & 0xFFu) != 0) | (((w1 & 0xFF00u) != 0) << 1)
                        | (((w1 & 0xFF0000u) != 0) << 2) | (((w1 & 0xFF000000u) != 0) << 3);
        unsigned int b2 = ((w2 & 0xFFu) != 0) | (((w2 & 0xFF00u) != 0) << 1)
                        | (((w2 & 0xFF0000u) != 0) << 2) | (((w2 & 0xFF000000u) != 0) << 3);
        unsigned int b3 = ((w3 & 0xFFu) != 0) | (((w3 & 0xFF00u) != 0) << 1)
                        | (((w3 & 0xFF0000u) != 0) << 2) | (((w3 & 0xFF000000u) != 0) << 3);
        nz[4 * j + 0] = b0; nz[4 * j + 1] = b1; nz[4 * j + 2] = b2; nz[4 * j + 3] = b3;
        cnt += __popc(b0) + __popc(b1) + __popc(b2) + __popc(b3);
      }
    } else {
      const uint4* mv = (const uint4*)maskb + (size_t)tid * 32;
      #pragma unroll
      for (int j = 0; j < 32; ++j){
        uint4 v = mv[j];
        unsigned int b = (v.x != 0) | ((v.y != 0) << 1)
                       | ((v.z != 0) << 2) | ((v.w != 0) << 3);
        nz[j] = b;
        cnt += __popc(b);
      }
    }
    cnts[tid] = cnt;
    __syncthreads();
    for (int off = 1; off < 256; off <<= 1){
      int v = cnts[tid];
      int u = (tid >= off) ? cnts[tid - off] : 0;
      __syncthreads();
      cnts[tid] = v + u;
      __syncthreads();
    }
    const int nact = cnts[255];
    const int base = tid * 128;
    int wofsA = cnts[tid] - cnt;               // exclusive active offset
    int wofsI = nact + base - wofsA;           // exclusive inactive offset
    #pragma unroll
    for (int j = 0; j < 32; ++j){
      unsigned int b = nz[j];
      #pragma unroll
      for (int s = 0; s < 4; ++s){
        const int bt = base + 4 * j + s;
        if (b & (1u << s)) idxb[wofsA++] = bt;
        else               idxb[wofsI++] = bt;
      }
    }
    if (tid == 255) *nactp = nact;
    return;
  }

  const int k = blockIdx.x;
  const int row = tid & 63;
  const int ch  = tid >> 6;        // column chunk: cols [ch*32, ch*32+32) of 128
  const int c0  = ch << 5;

  __shared__ float pr[2][128];
  __shared__ float fc[2][64];
  __shared__ float diag[64];
  __shared__ float muk[64];
  __shared__ float vpart[2][64];
  __shared__ float Ediag[64];

  float Wr[32];
  if (ch < 2){
    const float* Pg = Psi + (size_t)k * 4096 + (size_t)row * 64 + c0;
    #pragma unroll
    for (int c = 0; c < 32; ++c) Wr[c] = Pg[c];
  } else {
    #pragma unroll
    for (int c = 0; c < 32; ++c) Wr[c] = ((c0 - 64 + c) == row) ? 1.f : 0.f;
  }
  if (tid < 64) muk[tid] = mu_k[k * 64 + tid];
  if (row == 0){
    #pragma unroll
    for (int c = 0; c < 32; ++c) pr[0][c0 + c] = Wr[c];
  }
  if (ch == 0) fc[0][row] = Wr[0];
  __syncthreads();

  for (int jh = 0; jh < 2; ++jh){
    #pragma unroll
    for (int jl = 0; jl < 32; ++jl){
      const int j = jh * 32 + jl;
      const int cur = j & 1, nxt = cur ^ 1;
      float piv = pr[cur][j];
      float f = fc[cur][row] * __builtin_amdgcn_rcpf(piv);
      if (row == j && ch == 0) diag[j] = piv;
      if (row != j){
        #pragma unroll
        for (int c = 0; c < 32; ++c) Wr[c] = fmaf(-f, pr[cur][c0 + c], Wr[c]);
      }
      if (j < 63){
        if (row == j + 1){
          #pragma unroll
          for (int c = 0; c < 32; ++c) pr[nxt][c0 + c] = Wr[c];
        }
        if (jl < 31){ if (ch == jh)     fc[nxt][row] = Wr[jl + 1]; }
        else        { if (ch == jh + 1) fc[nxt][row] = Wr[0]; }
      }
      __syncthreads();
    }
  }

  const float nu = nu_a[k];
  const int j_k = k >> 4, kck = k & 15;

  if (ch >= 2){
    const int h = ch - 2;                   // e-half this thread owns
    const float dinv = nu / diag[row];
    float vp = 0.f;
    #pragma unroll
    for (int c = 0; c < 32; ++c) vp = fmaf(Wr[c], muk[h * 32 + c], vp);
    vpart[h][row] = vp * dinv;
    // E-row scatter into symmetric pair-block layout (only bI <= bJ stored)
    const int d = row;
    const int bI = d >> 3;
    const int pch = (d >> 2) & 1;
    const int sHi = d & 3;                  // g-slot
    #pragma unroll
    for (int cc = 0; cc < 32; ++cc){
      const int e = h * 32 + cc;
      const int bJ = e >> 3;
      float val = Wr[cc] * dinv;
      if (e == d) Ediag[row] = val;
      if (bI <= bJ){
        const int pb = ((bJ * (bJ + 1)) >> 1) + bI;
        const int ci = pb * 2 + pch;
        const float sc = (bI < bJ) ? 2.f : 1.f;
        BG[(size_t)((ci * 3 + j_k) * 64 + kck * 4 + sHi) * 8 + (e & 7)] = (f16)(val * sc);
      }
    }
  }
  __syncthreads();

  if (tid < 64){
    const int t = tid;
    float v = vpart[0][t] + vpart[1][t];
    const int g = (t >> 3) & 3, q = t & 7;
    const int cA = 72 + (t >> 5);
    const int cB = 74 + (t >> 5);
    BG[(size_t)((cA * 3 + j_k) * 64 + kck * 4 + g) * 8 + q] = (f16)(-2.f * v);
    BG[(size_t)((cB * 3 + j_k) * 64 + kck * 4 + g) * 8 + q] = (f16)(Ediag[t]);
    float c2 = wsum64(v * muk[t]);
    float dg = wsum64(digammaf_((nu - (float)t) * 0.5f));
    float ld = wsum64(logf(diag[t]));
    if (t == 0){
      const float LN2   = 0.69314718055994531f;
      const float LN2PI = 1.83787706640934548f;
      float Elogdet = dg + 64.f * LN2 - ld;
      float cst = 0.5f * (Elogdet - 64.f * LN2PI);
      c0o[k] = cst - 0.5f * c2 - 32.f / kap_a[k];
    }
  }
}

// -------- kernel B: main (f16 MFMA x2 + k32 dot, compacted bt tiles) --------
#define BUILD(AF, FD, MUD)                                                 \
  {                                                                        \
    float s_[8];                                                           \
    _Pragma("unroll")                                                      \
    for (int q_ = 0; q_ < 8; ++q_) s_[q_] = (MUD) * mue[q_];               \
    _Pragma("unroll")                                                      \
    for (int r_ = 0; r_ < 4; ++r_){                                        \
      h2 fp_ = { (FD)[2 * r_], (FD)[2 * r_ + 1] };                         \
      _Pragma("unroll")                                                    \
      for (int q_ = 0; q_ < 8; ++q_){                                      \
        h2 ep_ = { FeT[q_][2 * r_], FeT[q_][2 * r_ + 1] };                 \
        s_[q_] = DOT2(fp_, ep_, s_[q_]);                                   \
      }                                                                    \
    }                                                                      \
    _Pragma("unroll")                                                      \
    for (int q_ = 0; q_ < 8; ++q_) (AF)[q_] = (f16)s_[q_];                 \
  }

#define MFMA2(AF, B0, B1)                                                  \
  acc0 = __builtin_amdgcn_mfma_f32_16x16x32_f16((AF), (B0), acc0, 0, 0, 0);\
  acc1 = __builtin_amdgcn_mfma_f32_16x16x32_f16((AF), (B1), acc1, 0, 0, 0);

#define K32DOT(AF, B32)                                                    \
  {                                                                        \
    h2q afq_ = __builtin_bit_cast(h2q, (AF));                              \
    h2q bq_  = __builtin_bit_cast(h2q, (B32));                             \
    _Pragma("unroll")                                                      \
    for (int r_ = 0; r_ < 4; ++r_)                                         \
      acc32 = DOT2(afq_.p[r_], bq_.p[r_], acc32);                          \
  }

__global__ __launch_bounds__(128) void main_kernel(
    const float* __restrict__ mu_t, const float* __restrict__ var_t,
    const float* __restrict__ F_t,
    const f16* __restrict__ BG, const float* __restrict__ c0o,
    const int* __restrict__ nactp, const int* __restrict__ idxb,
    float* __restrict__ out)
{
  __shared__ __align__(16) f16 sG[BT_BLK][64][8];  // F[d][r], d^(bt&7); 16384 B
  __shared__ __align__(16) f16 sMu[BT_BLK][64];    // block-8 d-swizzle;  2048 B
  __shared__ int sIdx[BT_BLK];

  const int tid = threadIdx.x;
  const int l = tid & 63;
  const int xh = tid >> 6;               // wave = pair-range half
  const int g = l >> 4;
  const int kc = l & 15;
  const int btl = kc;                    // this lane's local A row
  const int btSw = btl & 7;

  const int nact = *nactp;
  const int t0 = blockIdx.x * BT_BLK;
  const int nLoc = min(BT_BLK, max(0, nact - t0));   // active rows in tile

  if (tid < BT_BLK) sIdx[tid] = idxb[t0 + tid];      // full list: always valid
  __syncthreads();

  // ---- zero-fill inactive rows of this tile (rows nLoc..16) ----
  for (int i = tid; i < (BT_BLK - nLoc) * 33; i += 128){
    const int r = nLoc + i / 33;
    out[(size_t)sIdx[r] * 33 + (i % 33)] = 0.f;
  }
  if (nLoc == 0) return;                 // fully inactive tile: done

  // ---- stage F / mu into LDS (coalesced per row, f32->f16, via idx) ----
  {
    #pragma unroll
    for (int ii = 0; ii < 16; ++ii){
      int i = tid + ii * 128;
      int bt = i >> 7, rem = i & 127, d = rem >> 1, rb = (rem & 1) << 2;
      const float4* fg = (const float4*)(F_t + (size_t)sIdx[bt] * 512);
      float4 f = fg[rem];
      int dsw = d ^ (bt & 7);
      f16x4 ff = { (f16)f.x, (f16)f.y, (f16)f.z, (f16)f.w };
      *(f16x4*)&sG[bt][dsw][rb] = ff;
    }
    #pragma unroll
    for (int ii = 0; ii < 2; ++ii){
      int i = tid + ii * 128;
      int bt = i >> 4, e4 = i & 15, d0 = e4 << 2;
      const float4* mg = (const float4*)(mu_t + (size_t)sIdx[bt] * 64);
      float4 m4 = mg[e4];
      int dsw = (((d0 >> 3) ^ (bt & 7)) << 3) | (d0 & 7);
      f16x4 mm = { (f16)m4.x, (f16)m4.y, (f16)m4.z, (f16)m4.w };
      *(f16x4*)&sMu[bt][dsw] = mm;
    }
  }
  __syncthreads();

  // per-wave pair range: wave0 = pairs [0,19), wave1 = pairs [19,36) + ext
  const int ppStart = xh ? 19 : 0;
  const int ppEnd   = xh ? 36 : 19;

  f32x4 acc0 = {0.f,0.f,0.f,0.f}, acc1 = {0.f,0.f,0.f,0.f};
  float acc32 = 0.f;

  f16x8 FeT[8];      // F rows e = bJ*8+q (reloaded per bJ)
  float mue[8];

  const f16* bp   = BG + (size_t)(ppStart * 2) * 1536 + (size_t)(kc * 4 + g) * 8;
  const f16* bp32 = BG + (size_t)(ppStart * 2) * 1536 + 1024 + (size_t)g * 8;

  // prologue: stage A = chunk 2*ppStart, stage B = chunk 2*ppStart+1
  const int bI0 = PB_BI[ppStart];
  f16x8 fdA = *(const f16x8*)&sG[btl][(bI0 * 8 + g) ^ btSw][0];
  f16x8 fdB = *(const f16x8*)&sG[btl][(bI0 * 8 + 4 + g) ^ btSw][0];
  float mudA = (float)sMu[btl][((bI0 ^ btSw) << 3) | g];
  float mudB = (float)sMu[btl][((bI0 ^ btSw) << 3) | (4 + g)];

  f16x8 a0 = *(const f16x8*)(bp);
  f16x8 a1 = *(const f16x8*)(bp + 512);
  f16x8 b0v = *(const f16x8*)(bp + 1536);
  f16x8 b1v = *(const f16x8*)(bp + 1536 + 512);
  f16x8 w0v = *(const f16x8*)(bp32);
  f16x8 w1v = *(const f16x8*)(bp32 + 1536);
  bp += 3072;
  bp32 += 3072;

  int curBJ = -1;
  for (int pp = ppStart; pp < ppEnd; ++pp){
    const int bJ = PB_BJ[pp];
    if (bJ != curBJ){
      curBJ = bJ;
      #pragma unroll
      for (int q = 0; q < 8; ++q)
        FeT[q] = *(const f16x8*)&sG[btl][((bJ << 3) + q) ^ btSw][0];
      f16x8 mr = *(const f16x8*)&sMu[btl][((bJ ^ btSw) << 3)];
      #pragma unroll
      for (int q = 0; q < 8; ++q) mue[q] = (float)mr[q];
    }
    const int bIn = PB_BI[pp + 1];
    // ---- even chunk (stage A), refill with next pair's p=0 ----
    {
      f16x8 af;
      BUILD(af, fdA, mudA);
      MFMA2(af, a0, a1);
      K32DOT(af, w0v);
      a0 = *(const f16x8*)(bp);
      a1 = *(const f16x8*)(bp + 512);
      w0v = *(const f16x8*)(bp32);
      fdA = *(const f16x8*)&sG[btl][(bIn * 8 + g) ^ btSw][0];
      mudA = (float)sMu[btl][((bIn ^ btSw) << 3) | g];
    }
    // ---- odd chunk (stage B), refill with next pair's p=1 ----
    {
      f16x8 af;
      BUILD(af, fdB, mudB);
      MFMA2(af, b0v, b1v);
      K32DOT(af, w1v);
      b0v = *(const f16x8*)(bp + 1536);
      b1v = *(const f16x8*)(bp + 1536 + 512);
      w1v = *(const f16x8*)(bp32 + 1536);
      fdB = *(const f16x8*)&sG[btl][(bIn * 8 + 4 + g) ^ btSw][0];
      mudB = (float)sMu[btl][((bIn ^ btSw) << 3) | (4 + g)];
    }
    bp += 3072;
    bp32 += 3072;
  }

  // ---- ext chunks (wave 1 only), ABSOLUTE addressing at chunk 72 ----
  if (xh == 1){
    const f16* bpe   = BG + (size_t)72 * 1536 + (size_t)(kc * 4 + g) * 8;
    const f16* bpe32 = BG + (size_t)72 * 1536 + 1024 + (size_t)g * 8;
    #pragma unroll
    for (int m = 0; m < 4; ++m){
      f16x8 af;
      if (m < 2){
        af = *(const f16x8*)&sMu[btl][(((m * 4 + g) ^ btSw) << 3)];
      } else {
        const float* vr = var_t + (size_t)sIdx[btl] * 64 + (m - 2) * 32 + g * 8;
        f32x4 va = *(const f32x4*)(vr);
        f32x4 vb = *(const f32x4*)(vr + 4);
        #pragma unroll
        for (int r = 0; r < 4; ++r){ af[r] = (f16)va[r]; af[4 + r] = (f16)vb[r]; }
      }
      f16x8 e0 = *(const f16x8*)(bpe);
      f16x8 e1 = *(const f16x8*)(bpe + 512);
      f16x8 e32 = *(const f16x8*)(bpe32);
      MFMA2(af, e0, e1);
      K32DOT(af, e32);
      bpe += 1536;
      bpe32 += 1536;
    }
  }

  // ---- cross-wave reduce (aliased into sG after barrier) ----
  __syncthreads();                         // all waves done reading sG/sMu
  float* sRedF = (float*)sG;               // [64][9] floats = 2304 B
  if (xh == 1){
    const int bofs = l * 9;
    #pragma unroll
    for (int r = 0; r < 4; ++r){
      sRedF[bofs + r]     = acc0[r];
      sRedF[bofs + 4 + r] = acc1[r];
    }
    sRedF[bofs + 8] = acc32;
  }
  __syncthreads();
  if (xh == 0){
    const int bofs = l * 9;
    #pragma unroll
    for (int r = 0; r < 4; ++r){
      acc0[r] += sRedF[bofs + r];
      acc1[r] += sRedF[bofs + 4 + r];
    }
    acc32 += sRedF[bofs + 8];
    // g-reduce k32 (lanes same kc, different g)
    acc32 += __shfl_xor(acc32, 16);
    acc32 += __shfl_xor(acc32, 32);

    float c0a = c0o[kc];
    float c0b = c0o[16 + kc];
    float c0c = c0o[32];
    #pragma unroll
    for (int reg = 0; reg < 4; ++reg){
      int r16 = g * 4 + reg;
      if (r16 < nLoc){
        float* op = out + (size_t)sIdx[r16] * 33;
        op[kc]      = fmaf(-0.5f, acc0[reg], c0a);
        op[16 + kc] = fmaf(-0.5f, acc1[reg], c0b);
      }
    }
    if (g == 0 && kc < nLoc){
      out[(size_t)sIdx[kc] * 33 + 32] = fmaf(-0.5f, acc32, c0c);
    }
  }
}

// --------------------------- launch -----------------------------------------
extern "C" void kernel_launch(void* const* d_in, const int* in_sizes, int n_in,
                              void* d_out, int out_size, void* d_ws, size_t ws_size,
                              hipStream_t stream)
{
  const float* mu_t  = (const float*)d_in[0];
  const float* var_t = (const float*)d_in[1];
  const float* F_t   = (const float*)d_in[2];
  const float* mu_k  = (const float*)d_in[3];
  const float* Psi   = (const float*)d_in[4];
  const float* nu    = (const float*)d_in[5];
  const float* kap   = (const float*)d_in[6];
  const unsigned char* mask = (const unsigned char*)d_in[7];

  f16*   BG   = (f16*)d_ws;                             // 233472 B
  float* c0o  = (float*)((char*)d_ws + 233472);         // 132 B
  int*   nact = (int*)((char*)d_ws + 233472 + 256);     // 4 B
  int*   idxb = nact + 1;                               // 131072 B
  float* outp = (float*)d_out;

  hipLaunchKernelGGL(prep_kernel, dim3(34), dim3(256), 0, stream,
                     mu_k, Psi, nu, kap, mask, BG, c0o, nact, idxb);
  hipLaunchKernelGGL(main_kernel, dim3(BT_TOTAL / BT_BLK), dim3(128), 0, stream,
                     mu_t, var_t, F_t, BG, c0o, nact, idxb, outp);
}

// Round 22
// 56.751 us; speedup vs baseline: 1.4017x; 1.1777x over previous
//
#include <hip/hip_runtime.h>

// ---------------------------------------------------------------------------
// StickyHDPHMMVI emission log-likelihood, f16 MFMA + symmetry + mask-compact:
// out[bt,k] = c0_k - 0.5 * sum_x A[bt,x] * B[k,x]   (masked bt -> 0)
// x enumerates SYMMETRIC pair-blocks (bI<=bJ) of the 64x64 (d,e) space:
//   pair pb=(bI,bJ), chunks c = pb*2+p (p=0,1), slot s = g*8+q:
//     d = bI*8 + p*4 + g, e = bJ*8 + q
//     A = S0[d][e] (mu muT + F FT),  B = E_k[d][e] * (bI<bJ ? 2 : 1)
//   c=72,73: A = mu[t],  B = -2*v_k[t];  c=74,75: A = var[t], B = E_k[t,t]
// B lane-ordered: BG[((c*3 + j)*64 + kc*4 + g)*8 + q], k = j*16+kc
// k columns 0..31 via TWO MFMA; k=32 via 4x v_dot2 + shfl g-reduce (r18).
// Mask compaction -> full permutation idxb (active then inactive); main's
// inactive tiles zero-fill and exit (r21; no runtime memset — r20's 40us fill).
// r22: prep GJ does TWO pivots per barrier round (32 rounds, was 64) — prep
// was ~27us of pure barrier-paced latency (VALUBusy ~1.5%). Two-pivot update:
// Wr -= coefA*rowA + coefB*rowB, coefA = f1 - f2*fJ1, coefB = f2, verified
// per-case (row j / j+1 / general) == two sequential GJ steps.
// Refuted-null pile: addressing(r13), reg budget(r15), forced occupancy
// (r11 spill storm), L1 pairing(r16), LDS ring(r17). Work cuts always paid.
// ---------------------------------------------------------------------------

#define BT_TOTAL 32768
#define BT_BLK 16
#define NCHUNK 76

typedef _Float16 f16;
typedef __attribute__((ext_vector_type(8))) _Float16 f16x8;
typedef __attribute__((ext_vector_type(4))) _Float16 f16x4;
typedef __attribute__((ext_vector_type(2))) _Float16 h2;
typedef __attribute__((ext_vector_type(4))) float f32x4;
typedef struct { h2 p[4]; } h2q;

#if __has_builtin(__builtin_amdgcn_fdot2)
#define DOT2(a, b, c) __builtin_amdgcn_fdot2((a), (b), (c), false)
#else
#define DOT2(a, b, c) fmaf((float)(a)[0], (float)(b)[0], fmaf((float)(a)[1], (float)(b)[1], (c)))
#endif

// pair-block tables (bJ outer 0..7, bI inner 0..bJ), +1 guard entry
__constant__ unsigned char PB_BJ[37] =
  {0, 1,1, 2,2,2, 3,3,3,3, 4,4,4,4,4, 5,5,5,5,5,5, 6,6,6,6,6,6,6, 7,7,7,7,7,7,7,7, 7};
__constant__ unsigned char PB_BI[37] =
  {0, 0,1, 0,1,2, 0,1,2,3, 0,1,2,3,4, 0,1,2,3,4,5, 0,1,2,3,4,5,6, 0,1,2,3,4,5,6,7, 7};

__device__ __forceinline__ float digammaf_(float x){
  float r = 0.f;
  while (x < 6.f){ r -= 1.f / x; x += 1.f; }
  float xi = 1.f / x;
  float xi2 = xi * xi;
  return r + logf(x) - 0.5f * xi
         - xi2 * (0.083333333333f - xi2 * (0.0083333333333f - xi2 * 0.0039682539683f));
}

__device__ __forceinline__ float wsum64(float x){
  #pragma unroll
  for (int o = 32; o > 0; o >>= 1) x += __shfl_down(x, o);
  return x;  // valid in lane 0
}

// ---------- kernel A: per-k prep (blocks 0..32) + mask compact (block 33) ---
__global__ __launch_bounds__(256) void prep_kernel(
    const float* __restrict__ mu_k, const float* __restrict__ Psi,
    const float* __restrict__ nu_a, const float* __restrict__ kap_a,
    const unsigned char* __restrict__ maskb,
    f16* __restrict__ BG, float* __restrict__ c0o,
    int* __restrict__ nactp, int* __restrict__ idxb)
{
  const int tid = threadIdx.x;

  if (blockIdx.x == 33){
    // ---- mask compaction: full permutation (active then inactive) ----
    __shared__ int cnts[256];
    const int l = tid & 63;
    const bool byteMask =
        __any((maskb[4 * l + 1] | maskb[4 * l + 2] | maskb[4 * l + 3]) != 0);
    unsigned int nz[32];            // bit s of nz[j] = flag of bt 4j+s
    int cnt = 0;
    if (byteMask){
      const uint4* mv = (const uint4*)(maskb + (size_t)tid * 128);
      #pragma unroll
      for (int j = 0; j < 8; ++j){
        uint4 v = mv[j];
        unsigned int w0 = v.x, w1 = v.y, w2 = v.z, w3 = v.w;
        unsigned int b0 = ((w0 & 0xFFu) != 0) | (((w0 & 0xFF00u) != 0) << 1)
                        | (((w0 & 0xFF0000u) != 0) << 2) | (((w0 & 0xFF000000u) != 0) << 3);
        unsigned int b1 = ((w1 & 0xFFu) != 0) | (((w1 & 0xFF00u) != 0) << 1)
                        | (((w1 & 0xFF0000u) != 0) << 2) | (((w1 & 0xFF000000u) != 0) << 3);
        unsigned int b2 = ((w2 & 0xFFu) != 0) | (((w2 & 0xFF00u) != 0) << 1)
                        | (((w2 & 0xFF0000u) != 0) << 2) | (((w2 & 0xFF000000u) != 0) << 3);
        unsigned int b3 = ((w3 & 0xFFu) != 0) | (((w3 & 0xFF00u) != 0) << 1)
                        | (((w3 & 0xFF0000u) != 0) << 2) | (((w3 & 0xFF000000u) != 0) << 3);
        nz[4 * j + 0] = b0; nz[4 * j + 1] = b1; nz[4 * j + 2] = b2; nz[4 * j + 3] = b3;
        cnt += __popc(b0) + __popc(b1) + __popc(b2) + __popc(b3);
      }
    } else {
      const uint4* mv = (const uint4*)maskb + (size_t)tid * 32;
      #pragma unroll
      for (int j = 0; j < 32; ++j){
        uint4 v = mv[j];
        unsigned int b = (v.x != 0) | ((v.y != 0) << 1)
                       | ((v.z != 0) << 2) | ((v.w != 0) << 3);
        nz[j] = b;
        cnt += __popc(b);
      }
    }
    cnts[tid] = cnt;
    __syncthreads();
    for (int off = 1; off < 256; off <<= 1){
      int v = cnts[tid];
      int u = (tid >= off) ? cnts[tid - off] : 0;
      __syncthreads();
      cnts[tid] = v + u;
      __syncthreads();
    }
    const int nact = cnts[255];
    const int base = tid * 128;
    int wofsA = cnts[tid] - cnt;               // exclusive active offset
    int wofsI = nact + base - wofsA;           // exclusive inactive offset
    #pragma unroll
    for (int j = 0; j < 32; ++j){
      unsigned int b = nz[j];
      #pragma unroll
      for (int s = 0; s < 4; ++s){
        const int bt = base + 4 * j + s;
        if (b & (1u << s)) idxb[wofsA++] = bt;
        else               idxb[wofsI++] = bt;
      }
    }
    if (tid == 255) *nactp = nact;
    return;
  }

  const int k = blockIdx.x;
  const int row = tid & 63;
  const int ch  = tid >> 6;        // column chunk: cols [ch*32, ch*32+32) of 128
  const int c0  = ch << 5;

  __shared__ float prA[2][128];
  __shared__ float prB[2][128];
  __shared__ float fcA[2][64];
  __shared__ float fcB[2][64];
  __shared__ float diag[64];
  __shared__ float muk[64];
  __shared__ float vpart[2][64];
  __shared__ float Ediag[64];

  float Wr[32];
  if (ch < 2){
    const float* Pg = Psi + (size_t)k * 4096 + (size_t)row * 64 + c0;
    #pragma unroll
    for (int c = 0; c < 32; ++c) Wr[c] = Pg[c];
  } else {
    #pragma unroll
    for (int c = 0; c < 32; ++c) Wr[c] = ((c0 - 64 + c) == row) ? 1.f : 0.f;
  }
  if (tid < 64) muk[tid] = mu_k[k * 64 + tid];
  // prologue: publish rows 0,1 and f-columns for pivots 0,1
  if (row == 0){
    #pragma unroll
    for (int c = 0; c < 32; ++c) prA[0][c0 + c] = Wr[c];
  }
  if (row == 1){
    #pragma unroll
    for (int c = 0; c < 32; ++c) prB[0][c0 + c] = Wr[c];
  }
  if (ch == 0){ fcA[0][row] = Wr[0]; fcB[0][row] = Wr[1]; }
  __syncthreads();

  // ---- two-pivot Gauss-Jordan: 32 barrier rounds ----
  #pragma unroll
  for (int jh = 0; jh < 2; ++jh){
    #pragma unroll
    for (int ml = 0; ml < 16; ++ml){
      const int m = jh * 16 + ml;
      const int j = 2 * m;
      const int cur = m & 1, nxt = cur ^ 1;
      const float pivA = prA[cur][j];
      const float rA1  = prA[cur][j + 1];
      const float rcpA = __builtin_amdgcn_rcpf(pivA);
      const float fJ1  = fcA[cur][j + 1] * rcpA;
      const float pivB = fmaf(-fJ1, rA1, prB[cur][j + 1]);
      const float rcpB = __builtin_amdgcn_rcpf(pivB);
      const float f1 = (row == j) ? 0.f : fcA[cur][row] * rcpA;
      const float v1 = (row == j) ? rA1 : fmaf(-f1, rA1, fcB[cur][row]);
      const float f2 = (row == j + 1) ? 0.f : v1 * rcpB;
      const float coefA = fmaf(-f2, fJ1, f1);
      const float coefB = f2;
      if (tid == 0){ diag[j] = pivA; diag[j + 1] = pivB; }
      #pragma unroll
      for (int c = 0; c < 32; ++c)
        Wr[c] = fmaf(-coefA, prA[cur][c0 + c],
                fmaf(-coefB, prB[cur][c0 + c], Wr[c]));
      if (m < 31){
        const int jn2 = j + 2, jn3 = j + 3;
        if (row == jn2){
          #pragma unroll
          for (int c = 0; c < 32; ++c) prA[nxt][c0 + c] = Wr[c];
        }
        if (row == jn3){
          #pragma unroll
          for (int c = 0; c < 32; ++c) prB[nxt][c0 + c] = Wr[c];
        }
        if (ch == (jn2 >> 5)) fcA[nxt][row] = Wr[jn2 & 31];
        if (ch == (jn3 >> 5)) fcB[nxt][row] = Wr[jn3 & 31];
      }
      __syncthreads();
    }
  }

  const float nu = nu_a[k];
  const int j_k = k >> 4, kck = k & 15;

  if (ch >= 2){
    const int h = ch - 2;                   // e-half this thread owns
    const float dinv = nu / diag[row];
    float vp = 0.f;
    #pragma unroll
    for (int c = 0; c < 32; ++c) vp = fmaf(Wr[c], muk[h * 32 + c], vp);
    vpart[h][row] = vp * dinv;
    // E-row scatter into symmetric pair-block layout (only bI <= bJ stored)
    const int d = row;
    const int bI = d >> 3;
    const int pch = (d >> 2) & 1;
    const int sHi = d & 3;                  // g-slot
    #pragma unroll
    for (int cc = 0; cc < 32; ++cc){
      const int e = h * 32 + cc;
      const int bJ = e >> 3;
      float val = Wr[cc] * dinv;
      if (e == d) Ediag[row] = val;
      if (bI <= bJ){
        const int pb = ((bJ * (bJ + 1)) >> 1) + bI;
        const int ci = pb * 2 + pch;
        const float sc = (bI < bJ) ? 2.f : 1.f;
        BG[(size_t)((ci * 3 + j_k) * 64 + kck * 4 + sHi) * 8 + (e & 7)] = (f16)(val * sc);
      }
    }
  }
  __syncthreads();

  if (tid < 64){
    const int t = tid;
    float v = vpart[0][t] + vpart[1][t];
    const int g = (t >> 3) & 3, q = t & 7;
    const int cA = 72 + (t >> 5);
    const int cB = 74 + (t >> 5);
    BG[(size_t)((cA * 3 + j_k) * 64 + kck * 4 + g) * 8 + q] = (f16)(-2.f * v);
    BG[(size_t)((cB * 3 + j_k) * 64 + kck * 4 + g) * 8 + q] = (f16)(Ediag[t]);
    float c2 = wsum64(v * muk[t]);
    float dg = wsum64(digammaf_((nu - (float)t) * 0.5f));
    float ld = wsum64(logf(diag[t]));
    if (t == 0){
      const float LN2   = 0.69314718055994531f;
      const float LN2PI = 1.83787706640934548f;
      float Elogdet = dg + 64.f * LN2 - ld;
      float cst = 0.5f * (Elogdet - 64.f * LN2PI);
      c0o[k] = cst - 0.5f * c2 - 32.f / kap_a[k];
    }
  }
}

// -------- kernel B: main (f16 MFMA x2 + k32 dot, compacted bt tiles) --------
#define BUILD(AF, FD, MUD)                                                 \
  {                                                                        \
    float s_[8];                                                           \
    _Pragma("unroll")                                                      \
    for (int q_ = 0; q_ < 8; ++q_) s_[q_] = (MUD) * mue[q_];               \
    _Pragma("unroll")                                                      \
    for (int r_ = 0; r_ < 4; ++r_){                                        \
      h2 fp_ = { (FD)[2 * r_], (FD)[2 * r_ + 1] };                         \
      _Pragma("unroll")                                                    \
      for (int q_ = 0; q_ < 8; ++q_){                                      \
        h2 ep_ = { FeT[q_][2 * r_], FeT[q_][2 * r_ + 1] };                 \
        s_[q_] = DOT2(fp_, ep_, s_[q_]);                                   \
      }                                                                    \
    }                                                                      \
    _Pragma("unroll")                                                      \
    for (int q_ = 0; q_ < 8; ++q_) (AF)[q_] = (f16)s_[q_];                 \
  }

#define MFMA2(AF, B0, B1)                                                  \
  acc0 = __builtin_amdgcn_mfma_f32_16x16x32_f16((AF), (B0), acc0, 0, 0, 0);\
  acc1 = __builtin_amdgcn_mfma_f32_16x16x32_f16((AF), (B1), acc1, 0, 0, 0);

#define K32DOT(AF, B32)                                                    \
  {                                                                        \
    h2q afq_ = __builtin_bit_cast(h2q, (AF));                              \
    h2q bq_  = __builtin_bit_cast(h2q, (B32));                             \
    _Pragma("unroll")                                                      \
    for (int r_ = 0; r_ < 4; ++r_)                                         \
      acc32 = DOT2(afq_.p[r_], bq_.p[r_], acc32);                          \
  }

__global__ __launch_bounds__(128) void main_kernel(
    const float* __restrict__ mu_t, const float* __restrict__ var_t,
    const float* __restrict__ F_t,
    const f16* __restrict__ BG, const float* __restrict__ c0o,
    const int* __restrict__ nactp, const int* __restrict__ idxb,
    float* __restrict__ out)
{
  __shared__ __align__(16) f16 sG[BT_BLK][64][8];  // F[d][r], d^(bt&7); 16384 B
  __shared__ __align__(16) f16 sMu[BT_BLK][64];    // block-8 d-swizzle;  2048 B
  __shared__ int sIdx[BT_BLK];

  const int tid = threadIdx.x;
  const int l = tid & 63;
  const int xh = tid >> 6;               // wave = pair-range half
  const int g = l >> 4;
  const int kc = l & 15;
  const int btl = kc;                    // this lane's local A row
  const int btSw = btl & 7;

  const int nact = *nactp;
  const int t0 = blockIdx.x * BT_BLK;
  const int nLoc = min(BT_BLK, max(0, nact - t0));   // active rows in tile

  if (tid < BT_BLK) sIdx[tid] = idxb[t0 + tid];      // full list: always valid
  __syncthreads();

  // ---- zero-fill inactive rows of this tile (rows nLoc..16) ----
  for (int i = tid; i < (BT_BLK - nLoc) * 33; i += 128){
    const int r = nLoc + i / 33;
    out[(size_t)sIdx[r] * 33 + (i % 33)] = 0.f;
  }
  if (nLoc == 0) return;                 // fully inactive tile: done

  // ---- stage F / mu into LDS (coalesced per row, f32->f16, via idx) ----
  {
    #pragma unroll
    for (int ii = 0; ii < 16; ++ii){
      int i = tid + ii * 128;
      int bt = i >> 7, rem = i & 127, d = rem >> 1, rb = (rem & 1) << 2;
      const float4* fg = (const float4*)(F_t + (size_t)sIdx[bt] * 512);
      float4 f = fg[rem];
      int dsw = d ^ (bt & 7);
      f16x4 ff = { (f16)f.x, (f16)f.y, (f16)f.z, (f16)f.w };
      *(f16x4*)&sG[bt][dsw][rb] = ff;
    }
    #pragma unroll
    for (int ii = 0; ii < 2; ++ii){
      int i = tid + ii * 128;
      int bt = i >> 4, e4 = i & 15, d0 = e4 << 2;
      const float4* mg = (const float4*)(mu_t + (size_t)sIdx[bt] * 64);
      float4 m4 = mg[e4];
      int dsw = (((d0 >> 3) ^ (bt & 7)) << 3) | (d0 & 7);
      f16x4 mm = { (f16)m4.x, (f16)m4.y, (f16)m4.z, (f16)m4.w };
      *(f16x4*)&sMu[bt][dsw] = mm;
    }
  }
  __syncthreads();

  // per-wave pair range: wave0 = pairs [0,19), wave1 = pairs [19,36) + ext
  const int ppStart = xh ? 19 : 0;
  const int ppEnd   = xh ? 36 : 19;

  f32x4 acc0 = {0.f,0.f,0.f,0.f}, acc1 = {0.f,0.f,0.f,0.f};
  float acc32 = 0.f;

  f16x8 FeT[8];      // F rows e = bJ*8+q (reloaded per bJ)
  float mue[8];

  const f16* bp   = BG + (size_t)(ppStart * 2) * 1536 + (size_t)(kc * 4 + g) * 8;
  const f16* bp32 = BG + (size_t)(ppStart * 2) * 1536 + 1024 + (size_t)g * 8;

  // prologue: stage A = chunk 2*ppStart, stage B = chunk 2*ppStart+1
  const int bI0 = PB_BI[ppStart];
  f16x8 fdA = *(const f16x8*)&sG[btl][(bI0 * 8 + g) ^ btSw][0];
  f16x8 fdB = *(const f16x8*)&sG[btl][(bI0 * 8 + 4 + g) ^ btSw][0];
  float mudA = (float)sMu[btl][((bI0 ^ btSw) << 3) | g];
  float mudB = (float)sMu[btl][((bI0 ^ btSw) << 3) | (4 + g)];

  f16x8 a0 = *(const f16x8*)(bp);
  f16x8 a1 = *(const f16x8*)(bp + 512);
  f16x8 b0v = *(const f16x8*)(bp + 1536);
  f16x8 b1v = *(const f16x8*)(bp + 1536 + 512);
  f16x8 w0v = *(const f16x8*)(bp32);
  f16x8 w1v = *(const f16x8*)(bp32 + 1536);
  bp += 3072;
  bp32 += 3072;

  int curBJ = -1;
  for (int pp = ppStart; pp < ppEnd; ++pp){
    const int bJ = PB_BJ[pp];
    if (bJ != curBJ){
      curBJ = bJ;
      #pragma unroll
      for (int q = 0; q < 8; ++q)
        FeT[q] = *(const f16x8*)&sG[btl][((bJ << 3) + q) ^ btSw][0];
      f16x8 mr = *(const f16x8*)&sMu[btl][((bJ ^ btSw) << 3)];
      #pragma unroll
      for (int q = 0; q < 8; ++q) mue[q] = (float)mr[q];
    }
    const int bIn = PB_BI[pp + 1];
    // ---- even chunk (stage A), refill with next pair's p=0 ----
    {
      f16x8 af;
      BUILD(af, fdA, mudA);
      MFMA2(af, a0, a1);
      K32DOT(af, w0v);
      a0 = *(const f16x8*)(bp);
      a1 = *(const f16x8*)(bp + 512);
      w0v = *(const f16x8*)(bp32);
      fdA = *(const f16x8*)&sG[btl][(bIn * 8 + g) ^ btSw][0];
      mudA = (float)sMu[btl][((bIn ^ btSw) << 3) | g];
    }
    // ---- odd chunk (stage B), refill with next pair's p=1 ----
    {
      f16x8 af;
      BUILD(af, fdB, mudB);
      MFMA2(af, b0v, b1v);
      K32DOT(af, w1v);
      b0v = *(const f16x8*)(bp + 1536);
      b1v = *(const f16x8*)(bp + 1536 + 512);
      w1v = *(const f16x8*)(bp32 + 1536);
      fdB = *(const f16x8*)&sG[btl][(bIn * 8 + 4 + g) ^ btSw][0];
      mudB = (float)sMu[btl][((bIn ^ btSw) << 3) | (4 + g)];
    }
    bp += 3072;
    bp32 += 3072;
  }

  // ---- ext chunks (wave 1 only), ABSOLUTE addressing at chunk 72 ----
  if (xh == 1){
    const f16* bpe   = BG + (size_t)72 * 1536 + (size_t)(kc * 4 + g) * 8;
    const f16* bpe32 = BG + (size_t)72 * 1536 + 1024 + (size_t)g * 8;
    #pragma unroll
    for (int m = 0; m < 4; ++m){
      f16x8 af;
      if (m < 2){
        af = *(const f16x8*)&sMu[btl][(((m * 4 + g) ^ btSw) << 3)];
      } else {
        const float* vr = var_t + (size_t)sIdx[btl] * 64 + (m - 2) * 32 + g * 8;
        f32x4 va = *(const f32x4*)(vr);
        f32x4 vb = *(const f32x4*)(vr + 4);
        #pragma unroll
        for (int r = 0; r < 4; ++r){ af[r] = (f16)va[r]; af[4 + r] = (f16)vb[r]; }
      }
      f16x8 e0 = *(const f16x8*)(bpe);
      f16x8 e1 = *(const f16x8*)(bpe + 512);
      f16x8 e32 = *(const f16x8*)(bpe32);
      MFMA2(af, e0, e1);
      K32DOT(af, e32);
      bpe += 1536;
      bpe32 += 1536;
    }
  }

  // ---- cross-wave reduce (aliased into sG after barrier) ----
  __syncthreads();                         // all waves done reading sG/sMu
  float* sRedF = (float*)sG;               // [64][9] floats = 2304 B
  if (xh == 1){
    const int bofs = l * 9;
    #pragma unroll
    for (int r = 0; r < 4; ++r){
      sRedF[bofs + r]     = acc0[r];
      sRedF[bofs + 4 + r] = acc1[r];
    }
    sRedF[bofs + 8] = acc32;
  }
  __syncthreads();
  if (xh == 0){
    const int bofs = l * 9;
    #pragma unroll
    for (int r = 0; r < 4; ++r){
      acc0[r] += sRedF[bofs + r];
      acc1[r] += sRedF[bofs + 4 + r];
    }
    acc32 += sRedF[bofs + 8];
    // g-reduce k32 (lanes same kc, different g)
    acc32 += __shfl_xor(acc32, 16);
    acc32 += __shfl_xor(acc32, 32);

    float c0a = c0o[kc];
    float c0b = c0o[16 + kc];
    float c0c = c0o[32];
    #pragma unroll
    for (int reg = 0; reg < 4; ++reg){
      int r16 = g * 4 + reg;
      if (r16 < nLoc){
        float* op = out + (size_t)sIdx[r16] * 33;
        op[kc]      = fmaf(-0.5f, acc0[reg], c0a);
        op[16 + kc] = fmaf(-0.5f, acc1[reg], c0b);
      }
    }
    if (g == 0 && kc < nLoc){
      out[(size_t)sIdx[kc] * 33 + 32] = fmaf(-0.5f, acc32, c0c);
    }
  }
}

// --------------------------- launch -----------------------------------------
extern "C" void kernel_launch(void* const* d_in, const int* in_sizes, int n_in,
                              void* d_out, int out_size, void* d_ws, size_t ws_size,
                              hipStream_t stream)
{
  const float* mu_t  = (const float*)d_in[0];
  const float* var_t = (const float*)d_in[1];
  const float* F_t   = (const float*)d_in[2];
  const float* mu_k  = (const float*)d_in[3];
  const float* Psi   = (const float*)d_in[4];
  const float* nu    = (const float*)d_in[5];
  const float* kap   = (const float*)d_in[6];
  const unsigned char* mask = (const unsigned char*)d_in[7];

  f16*   BG   = (f16*)d_ws;                             // 233472 B
  float* c0o  = (float*)((char*)d_ws + 233472);         // 132 B
  int*   nact = (int*)((char*)d_ws + 233472 + 256);     // 4 B
  int*   idxb = nact + 1;                               // 131072 B
  float* outp = (float*)d_out;

  hipLaunchKernelGGL(prep_kernel, dim3(34), dim3(256), 0, stream,
                     mu_k, Psi, nu, kap, mask, BG, c0o, nact, idxb);
  hipLaunchKernelGGL(main_kernel, dim3(BT_TOTAL / BT_BLK), dim3(128), 0, stream,
                     mu_t, var_t, F_t, BG, c0o, nact, idxb, outp);
}

// Round 23
// 54.532 us; speedup vs baseline: 1.4588x; 1.0407x over previous
//
#include <hip/hip_runtime.h>

// ---------------------------------------------------------------------------
// StickyHDPHMMVI emission log-likelihood, f16 MFMA + symmetry + mask-compact:
// out[bt,k] = c0_k - 0.5 * sum_x A[bt,x] * B[k,x]   (masked bt -> 0)
// x enumerates SYMMETRIC pair-blocks (bI<=bJ) of the 64x64 (d,e) space:
//   pair pb=(bI,bJ), chunks c = pb*2+p (p=0,1), slot s = g*8+q:
//     d = bI*8 + p*4 + g, e = bJ*8 + q
//     A = S0[d][e] (mu muT + F FT),  B = E_k[d][e] * (bI<bJ ? 2 : 1)
//   c=72,73: A = mu[t],  B = -2*v_k[t];  c=74,75: A = var[t], B = E_k[t,t]
// B lane-ordered: BG[((c*3 + j)*64 + kc*4 + g)*8 + q], k = j*16+kc
// k cols 0..31 via TWO MFMA; k=32 via 4x v_dot2 + shfl g-reduce (r18).
// Compaction -> full permutation idxb; inactive tiles zero-fill + exit (r21).
// Two-pivot GJ prep, 32 barrier rounds (r22).
// r23: main uses FOUR waves/block (19-chunk serial chain per wave, was 38).
// At 2 active blocks' waves/SIMD post-compaction the chain is bare wall time;
// halving it should halve main (r12's 4-wave null was at 4 waves/SIMD).
// Refuted-null pile: addressing(r13), reg budget(r15), forced occupancy
// (r11 spill storm), L1 pairing(r16), LDS ring(r17).
// ---------------------------------------------------------------------------

#define BT_TOTAL 32768
#define BT_BLK 16
#define NCHUNK 76

typedef _Float16 f16;
typedef __attribute__((ext_vector_type(8))) _Float16 f16x8;
typedef __attribute__((ext_vector_type(4))) _Float16 f16x4;
typedef __attribute__((ext_vector_type(2))) _Float16 h2;
typedef __attribute__((ext_vector_type(4))) float f32x4;
typedef struct { h2 p[4]; } h2q;

#if __has_builtin(__builtin_amdgcn_fdot2)
#define DOT2(a, b, c) __builtin_amdgcn_fdot2((a), (b), (c), false)
#else
#define DOT2(a, b, c) fmaf((float)(a)[0], (float)(b)[0], fmaf((float)(a)[1], (float)(b)[1], (c)))
#endif

// pair-block tables (bJ outer 0..7, bI inner 0..bJ), +1 guard entry
__constant__ unsigned char PB_BJ[37] =
  {0, 1,1, 2,2,2, 3,3,3,3, 4,4,4,4,4, 5,5,5,5,5,5, 6,6,6,6,6,6,6, 7,7,7,7,7,7,7,7, 7};
__constant__ unsigned char PB_BI[37] =
  {0, 0,1, 0,1,2, 0,1,2,3, 0,1,2,3,4, 0,1,2,3,4,5, 0,1,2,3,4,5,6, 0,1,2,3,4,5,6,7, 7};

__device__ __forceinline__ float digammaf_(float x){
  float r = 0.f;
  while (x < 6.f){ r -= 1.f / x; x += 1.f; }
  float xi = 1.f / x;
  float xi2 = xi * xi;
  return r + logf(x) - 0.5f * xi
         - xi2 * (0.083333333333f - xi2 * (0.0083333333333f - xi2 * 0.0039682539683f));
}

__device__ __forceinline__ float wsum64(float x){
  #pragma unroll
  for (int o = 32; o > 0; o >>= 1) x += __shfl_down(x, o);
  return x;  // valid in lane 0
}

// ---------- kernel A: per-k prep (blocks 0..32) + mask compact (block 33) ---
__global__ __launch_bounds__(256) void prep_kernel(
    const float* __restrict__ mu_k, const float* __restrict__ Psi,
    const float* __restrict__ nu_a, const float* __restrict__ kap_a,
    const unsigned char* __restrict__ maskb,
    f16* __restrict__ BG, float* __restrict__ c0o,
    int* __restrict__ nactp, int* __restrict__ idxb)
{
  const int tid = threadIdx.x;

  if (blockIdx.x == 33){
    // ---- mask compaction: full permutation (active then inactive) ----
    __shared__ int cnts[256];
    const int l = tid & 63;
    const bool byteMask =
        __any((maskb[4 * l + 1] | maskb[4 * l + 2] | maskb[4 * l + 3]) != 0);
    unsigned int nz[32];            // bit s of nz[j] = flag of bt 4j+s
    int cnt = 0;
    if (byteMask){
      const uint4* mv = (const uint4*)(maskb + (size_t)tid * 128);
      #pragma unroll
      for (int j = 0; j < 8; ++j){
        uint4 v = mv[j];
        unsigned int w0 = v.x, w1 = v.y, w2 = v.z, w3 = v.w;
        unsigned int b0 = ((w0 & 0xFFu) != 0) | (((w0 & 0xFF00u) != 0) << 1)
                        | (((w0 & 0xFF0000u) != 0) << 2) | (((w0 & 0xFF000000u) != 0) << 3);
        unsigned int b1 = ((w1 & 0xFFu) != 0) | (((w1 & 0xFF00u) != 0) << 1)
                        | (((w1 & 0xFF0000u) != 0) << 2) | (((w1 & 0xFF000000u) != 0) << 3);
        unsigned int b2 = ((w2 & 0xFFu) != 0) | (((w2 & 0xFF00u) != 0) << 1)
                        | (((w2 & 0xFF0000u) != 0) << 2) | (((w2 & 0xFF000000u) != 0) << 3);
        unsigned int b3 = ((w3 & 0xFFu) != 0) | (((w3 & 0xFF00u) != 0) << 1)
                        | (((w3 & 0xFF0000u) != 0) << 2) | (((w3 & 0xFF000000u) != 0) << 3);
        nz[4 * j + 0] = b0; nz[4 * j + 1] = b1; nz[4 * j + 2] = b2; nz[4 * j + 3] = b3;
        cnt += __popc(b0) + __popc(b1) + __popc(b2) + __popc(b3);
      }
    } else {
      const uint4* mv = (const uint4*)maskb + (size_t)tid * 32;
      #pragma unroll
      for (int j = 0; j < 32; ++j){
        uint4 v = mv[j];
        unsigned int b = (v.x != 0) | ((v.y != 0) << 1)
                       | ((v.z != 0) << 2) | ((v.w != 0) << 3);
        nz[j] = b;
        cnt += __popc(b);
      }
    }
    cnts[tid] = cnt;
    __syncthreads();
    for (int off = 1; off < 256; off <<= 1){
      int v = cnts[tid];
      int u = (tid >= off) ? cnts[tid - off] : 0;
      __syncthreads();
      cnts[tid] = v + u;
      __syncthreads();
    }
    const int nact = cnts[255];
    const int base = tid * 128;
    int wofsA = cnts[tid] - cnt;               // exclusive active offset
    int wofsI = nact + base - wofsA;           // exclusive inactive offset
    #pragma unroll
    for (int j = 0; j < 32; ++j){
      unsigned int b = nz[j];
      #pragma unroll
      for (int s = 0; s < 4; ++s){
        const int bt = base + 4 * j + s;
        if (b & (1u << s)) idxb[wofsA++] = bt;
        else               idxb[wofsI++] = bt;
      }
    }
    if (tid == 255) *nactp = nact;
    return;
  }

  const int k = blockIdx.x;
  const int row = tid & 63;
  const int ch  = tid >> 6;        // column chunk: cols [ch*32, ch*32+32) of 128
  const int c0  = ch << 5;

  __shared__ float prA[2][128];
  __shared__ float prB[2][128];
  __shared__ float fcA[2][64];
  __shared__ float fcB[2][64];
  __shared__ float diag[64];
  __shared__ float muk[64];
  __shared__ float vpart[2][64];
  __shared__ float Ediag[64];

  float Wr[32];
  if (ch < 2){
    const float* Pg = Psi + (size_t)k * 4096 + (size_t)row * 64 + c0;
    #pragma unroll
    for (int c = 0; c < 32; ++c) Wr[c] = Pg[c];
  } else {
    #pragma unroll
    for (int c = 0; c < 32; ++c) Wr[c] = ((c0 - 64 + c) == row) ? 1.f : 0.f;
  }
  if (tid < 64) muk[tid] = mu_k[k * 64 + tid];
  if (row == 0){
    #pragma unroll
    for (int c = 0; c < 32; ++c) prA[0][c0 + c] = Wr[c];
  }
  if (row == 1){
    #pragma unroll
    for (int c = 0; c < 32; ++c) prB[0][c0 + c] = Wr[c];
  }
  if (ch == 0){ fcA[0][row] = Wr[0]; fcB[0][row] = Wr[1]; }
  __syncthreads();

  // ---- two-pivot Gauss-Jordan: 32 barrier rounds ----
  #pragma unroll
  for (int jh = 0; jh < 2; ++jh){
    #pragma unroll
    for (int ml = 0; ml < 16; ++ml){
      const int m = jh * 16 + ml;
      const int j = 2 * m;
      const int cur = m & 1, nxt = cur ^ 1;
      const float pivA = prA[cur][j];
      const float rA1  = prA[cur][j + 1];
      const float rcpA = __builtin_amdgcn_rcpf(pivA);
      const float fJ1  = fcA[cur][j + 1] * rcpA;
      const float pivB = fmaf(-fJ1, rA1, prB[cur][j + 1]);
      const float rcpB = __builtin_amdgcn_rcpf(pivB);
      const float f1 = (row == j) ? 0.f : fcA[cur][row] * rcpA;
      const float v1 = (row == j) ? rA1 : fmaf(-f1, rA1, fcB[cur][row]);
      const float f2 = (row == j + 1) ? 0.f : v1 * rcpB;
      const float coefA = fmaf(-f2, fJ1, f1);
      const float coefB = f2;
      if (tid == 0){ diag[j] = pivA; diag[j + 1] = pivB; }
      #pragma unroll
      for (int c = 0; c < 32; ++c)
        Wr[c] = fmaf(-coefA, prA[cur][c0 + c],
                fmaf(-coefB, prB[cur][c0 + c], Wr[c]));
      if (m < 31){
        const int jn2 = j + 2, jn3 = j + 3;
        if (row == jn2){
          #pragma unroll
          for (int c = 0; c < 32; ++c) prA[nxt][c0 + c] = Wr[c];
        }
        if (row == jn3){
          #pragma unroll
          for (int c = 0; c < 32; ++c) prB[nxt][c0 + c] = Wr[c];
        }
        if (ch == (jn2 >> 5)) fcA[nxt][row] = Wr[jn2 & 31];
        if (ch == (jn3 >> 5)) fcB[nxt][row] = Wr[jn3 & 31];
      }
      __syncthreads();
    }
  }

  const float nu = nu_a[k];
  const int j_k = k >> 4, kck = k & 15;

  if (ch >= 2){
    const int h = ch - 2;                   // e-half this thread owns
    const float dinv = nu / diag[row];
    float vp = 0.f;
    #pragma unroll
    for (int c = 0; c < 32; ++c) vp = fmaf(Wr[c], muk[h * 32 + c], vp);
    vpart[h][row] = vp * dinv;
    // E-row scatter into symmetric pair-block layout (only bI <= bJ stored)
    const int d = row;
    const int bI = d >> 3;
    const int pch = (d >> 2) & 1;
    const int sHi = d & 3;                  // g-slot
    #pragma unroll
    for (int cc = 0; cc < 32; ++cc){
      const int e = h * 32 + cc;
      const int bJ = e >> 3;
      float val = Wr[cc] * dinv;
      if (e == d) Ediag[row] = val;
      if (bI <= bJ){
        const int pb = ((bJ * (bJ + 1)) >> 1) + bI;
        const int ci = pb * 2 + pch;
        const float sc = (bI < bJ) ? 2.f : 1.f;
        BG[(size_t)((ci * 3 + j_k) * 64 + kck * 4 + sHi) * 8 + (e & 7)] = (f16)(val * sc);
      }
    }
  }
  __syncthreads();

  if (tid < 64){
    const int t = tid;
    float v = vpart[0][t] + vpart[1][t];
    const int g = (t >> 3) & 3, q = t & 7;
    const int cA = 72 + (t >> 5);
    const int cB = 74 + (t >> 5);
    BG[(size_t)((cA * 3 + j_k) * 64 + kck * 4 + g) * 8 + q] = (f16)(-2.f * v);
    BG[(size_t)((cB * 3 + j_k) * 64 + kck * 4 + g) * 8 + q] = (f16)(Ediag[t]);
    float c2 = wsum64(v * muk[t]);
    float dg = wsum64(digammaf_((nu - (float)t) * 0.5f));
    float ld = wsum64(logf(diag[t]));
    if (t == 0){
      const float LN2   = 0.69314718055994531f;
      const float LN2PI = 1.83787706640934548f;
      float Elogdet = dg + 64.f * LN2 - ld;
      float cst = 0.5f * (Elogdet - 64.f * LN2PI);
      c0o[k] = cst - 0.5f * c2 - 32.f / kap_a[k];
    }
  }
}

// -------- kernel B: main (f16 MFMA x2 + k32 dot, 4-wave, compacted) ---------
#define BUILD(AF, FD, MUD)                                                 \
  {                                                                        \
    float s_[8];                                                           \
    _Pragma("unroll")                                                      \
    for (int q_ = 0; q_ < 8; ++q_) s_[q_] = (MUD) * mue[q_];               \
    _Pragma("unroll")                                                      \
    for (int r_ = 0; r_ < 4; ++r_){                                        \
      h2 fp_ = { (FD)[2 * r_], (FD)[2 * r_ + 1] };                         \
      _Pragma("unroll")                                                    \
      for (int q_ = 0; q_ < 8; ++q_){                                      \
        h2 ep_ = { FeT[q_][2 * r_], FeT[q_][2 * r_ + 1] };                 \
        s_[q_] = DOT2(fp_, ep_, s_[q_]);                                   \
      }                                                                    \
    }                                                                      \
    _Pragma("unroll")                                                      \
    for (int q_ = 0; q_ < 8; ++q_) (AF)[q_] = (f16)s_[q_];                 \
  }

#define MFMA2(AF, B0, B1)                                                  \
  acc0 = __builtin_amdgcn_mfma_f32_16x16x32_f16((AF), (B0), acc0, 0, 0, 0);\
  acc1 = __builtin_amdgcn_mfma_f32_16x16x32_f16((AF), (B1), acc1, 0, 0, 0);

#define K32DOT(AF, B32)                                                    \
  {                                                                        \
    h2q afq_ = __builtin_bit_cast(h2q, (AF));                              \
    h2q bq_  = __builtin_bit_cast(h2q, (B32));                             \
    _Pragma("unroll")                                                      \
    for (int r_ = 0; r_ < 4; ++r_)                                         \
      acc32 = DOT2(afq_.p[r_], bq_.p[r_], acc32);                          \
  }

__global__ __launch_bounds__(256, 2) void main_kernel(
    const float* __restrict__ mu_t, const float* __restrict__ var_t,
    const float* __restrict__ F_t,
    const f16* __restrict__ BG, const float* __restrict__ c0o,
    const int* __restrict__ nactp, const int* __restrict__ idxb,
    float* __restrict__ out)
{
  __shared__ __align__(16) f16 sG[BT_BLK][64][8];  // F[d][r], d^(bt&7); 16384 B
  __shared__ __align__(16) f16 sMu[BT_BLK][64];    // block-8 d-swizzle;  2048 B
  __shared__ int sIdx[BT_BLK];

  const int tid = threadIdx.x;
  const int l = tid & 63;
  const int w = tid >> 6;                // wave = pair-range quarter (0..3)
  const int g = l >> 4;
  const int kc = l & 15;
  const int btl = kc;                    // this lane's local A row
  const int btSw = btl & 7;

  const int nact = *nactp;
  const int t0 = blockIdx.x * BT_BLK;
  const int nLoc = min(BT_BLK, max(0, nact - t0));   // active rows in tile

  if (tid < BT_BLK) sIdx[tid] = idxb[t0 + tid];      // full list: always valid
  __syncthreads();

  // ---- zero-fill inactive rows of this tile (rows nLoc..16) ----
  for (int i = tid; i < (BT_BLK - nLoc) * 33; i += 256){
    const int r = nLoc + i / 33;
    out[(size_t)sIdx[r] * 33 + (i % 33)] = 0.f;
  }
  if (nLoc == 0) return;                 // fully inactive tile: done

  // ---- stage F / mu into LDS (coalesced per row, f32->f16, via idx) ----
  {
    #pragma unroll
    for (int ii = 0; ii < 8; ++ii){
      int i = tid + ii * 256;
      int bt = i >> 7, rem = i & 127, d = rem >> 1, rb = (rem & 1) << 2;
      const float4* fg = (const float4*)(F_t + (size_t)sIdx[bt] * 512);
      float4 f = fg[rem];
      int dsw = d ^ (bt & 7);
      f16x4 ff = { (f16)f.x, (f16)f.y, (f16)f.z, (f16)f.w };
      *(f16x4*)&sG[bt][dsw][rb] = ff;
    }
    {
      int i = tid;                       // 256 float4 = 16 rows x 16
      int bt = i >> 4, e4 = i & 15, d0 = e4 << 2;
      const float4* mg = (const float4*)(mu_t + (size_t)sIdx[bt] * 64);
      float4 m4 = mg[e4];
      int dsw = (((d0 >> 3) ^ (bt & 7)) << 3) | (d0 & 7);
      f16x4 mm = { (f16)m4.x, (f16)m4.y, (f16)m4.z, (f16)m4.w };
      *(f16x4*)&sMu[bt][dsw] = mm;
    }
  }
  __syncthreads();

  // per-wave pair range: wave w = pairs [9w, 9w+9), ext chunk 72+w
  const int ppStart = 9 * w;
  const int ppEnd   = ppStart + 9;

  f32x4 acc0 = {0.f,0.f,0.f,0.f}, acc1 = {0.f,0.f,0.f,0.f};
  float acc32 = 0.f;

  f16x8 FeT[8];      // F rows e = bJ*8+q (reloaded per bJ)
  float mue[8];

  const f16* bp   = BG + (size_t)(ppStart * 2) * 1536 + (size_t)(kc * 4 + g) * 8;
  const f16* bp32 = BG + (size_t)(ppStart * 2) * 1536 + 1024 + (size_t)g * 8;

  // prologue: stage A = chunk 2*ppStart, stage B = chunk 2*ppStart+1
  const int bI0 = PB_BI[ppStart];
  f16x8 fdA = *(const f16x8*)&sG[btl][(bI0 * 8 + g) ^ btSw][0];
  f16x8 fdB = *(const f16x8*)&sG[btl][(bI0 * 8 + 4 + g) ^ btSw][0];
  float mudA = (float)sMu[btl][((bI0 ^ btSw) << 3) | g];
  float mudB = (float)sMu[btl][((bI0 ^ btSw) << 3) | (4 + g)];

  f16x8 a0 = *(const f16x8*)(bp);
  f16x8 a1 = *(const f16x8*)(bp + 512);
  f16x8 b0v = *(const f16x8*)(bp + 1536);
  f16x8 b1v = *(const f16x8*)(bp + 1536 + 512);
  f16x8 w0v = *(const f16x8*)(bp32);
  f16x8 w1v = *(const f16x8*)(bp32 + 1536);
  bp += 3072;
  bp32 += 3072;

  int curBJ = -1;
  for (int pp = ppStart; pp < ppEnd; ++pp){
    const int bJ = PB_BJ[pp];
    if (bJ != curBJ){
      curBJ = bJ;
      #pragma unroll
      for (int q = 0; q < 8; ++q)
        FeT[q] = *(const f16x8*)&sG[btl][((bJ << 3) + q) ^ btSw][0];
      f16x8 mr = *(const f16x8*)&sMu[btl][((bJ ^ btSw) << 3)];
      #pragma unroll
      for (int q = 0; q < 8; ++q) mue[q] = (float)mr[q];
    }
    const int bIn = PB_BI[pp + 1];
    // ---- even chunk (stage A), refill with next pair's p=0 ----
    {
      f16x8 af;
      BUILD(af, fdA, mudA);
      MFMA2(af, a0, a1);
      K32DOT(af, w0v);
      a0 = *(const f16x8*)(bp);
      a1 = *(const f16x8*)(bp + 512);
      w0v = *(const f16x8*)(bp32);
      fdA = *(const f16x8*)&sG[btl][(bIn * 8 + g) ^ btSw][0];
      mudA = (float)sMu[btl][((bIn ^ btSw) << 3) | g];
    }
    // ---- odd chunk (stage B), refill with next pair's p=1 ----
    {
      f16x8 af;
      BUILD(af, fdB, mudB);
      MFMA2(af, b0v, b1v);
      K32DOT(af, w1v);
      b0v = *(const f16x8*)(bp + 1536);
      b1v = *(const f16x8*)(bp + 1536 + 512);
      w1v = *(const f16x8*)(bp32 + 1536);
      fdB = *(const f16x8*)&sG[btl][(bIn * 8 + 4 + g) ^ btSw][0];
      mudB = (float)sMu[btl][((bIn ^ btSw) << 3) | (4 + g)];
    }
    bp += 3072;
    bp32 += 3072;
  }

  // ---- ext chunk 72+w (one per wave), ABSOLUTE addressing ----
  {
    const f16* bpe   = BG + (size_t)(72 + w) * 1536 + (size_t)(kc * 4 + g) * 8;
    const f16* bpe32 = BG + (size_t)(72 + w) * 1536 + 1024 + (size_t)g * 8;
    f16x8 af;
    if (w < 2){
      af = *(const f16x8*)&sMu[btl][(((w * 4 + g) ^ btSw) << 3)];
    } else {
      const float* vr = var_t + (size_t)sIdx[btl] * 64 + (w - 2) * 32 + g * 8;
      f32x4 va = *(const f32x4*)(vr);
      f32x4 vb = *(const f32x4*)(vr + 4);
      #pragma unroll
      for (int r = 0; r < 4; ++r){ af[r] = (f16)va[r]; af[4 + r] = (f16)vb[r]; }
    }
    f16x8 e0 = *(const f16x8*)(bpe);
    f16x8 e1 = *(const f16x8*)(bpe + 512);
    f16x8 e32 = *(const f16x8*)(bpe32);
    MFMA2(af, e0, e1);
    K32DOT(af, e32);
  }

  // ---- cross-wave reduce (aliased into sG after barrier) ----
  __syncthreads();                         // all waves done reading sG/sMu
  float* sRedF = (float*)sG;               // [3][64][9] floats = 6912 B
  if (w > 0){
    const int bofs = ((w - 1) * 64 + l) * 9;
    #pragma unroll
    for (int r = 0; r < 4; ++r){
      sRedF[bofs + r]     = acc0[r];
      sRedF[bofs + 4 + r] = acc1[r];
    }
    sRedF[bofs + 8] = acc32;
  }
  __syncthreads();
  if (w == 0){
    #pragma unroll
    for (int ww = 0; ww < 3; ++ww){
      const int bofs = (ww * 64 + l) * 9;
      #pragma unroll
      for (int r = 0; r < 4; ++r){
        acc0[r] += sRedF[bofs + r];
        acc1[r] += sRedF[bofs + 4 + r];
      }
      acc32 += sRedF[bofs + 8];
    }
    // g-reduce k32 (lanes same kc, different g)
    acc32 += __shfl_xor(acc32, 16);
    acc32 += __shfl_xor(acc32, 32);

    float c0a = c0o[kc];
    float c0b = c0o[16 + kc];
    float c0c = c0o[32];
    #pragma unroll
    for (int reg = 0; reg < 4; ++reg){
      int r16 = g * 4 + reg;
      if (r16 < nLoc){
        float* op = out + (size_t)sIdx[r16] * 33;
        op[kc]      = fmaf(-0.5f, acc0[reg], c0a);
        op[16 + kc] = fmaf(-0.5f, acc1[reg], c0b);
      }
    }
    if (g == 0 && kc < nLoc){
      out[(size_t)sIdx[kc] * 33 + 32] = fmaf(-0.5f, acc32, c0c);
    }
  }
}

// --------------------------- launch -----------------------------------------
extern "C" void kernel_launch(void* const* d_in, const int* in_sizes, int n_in,
                              void* d_out, int out_size, void* d_ws, size_t ws_size,
                              hipStream_t stream)
{
  const float* mu_t  = (const float*)d_in[0];
  const float* var_t = (const float*)d_in[1];
  const float* F_t   = (const float*)d_in[2];
  const float* mu_k  = (const float*)d_in[3];
  const float* Psi   = (const float*)d_in[4];
  const float* nu    = (const float*)d_in[5];
  const float* kap   = (const float*)d_in[6];
  const unsigned char* mask = (const unsigned char*)d_in[7];

  f16*   BG   = (f16*)d_ws;                             // 233472 B
  float* c0o  = (float*)((char*)d_ws + 233472);         // 132 B
  int*   nact = (int*)((char*)d_ws + 233472 + 256);     // 4 B
  int*   idxb = nact + 1;                               // 131072 B
  float* outp = (float*)d_out;

  hipLaunchKernelGGL(prep_kernel, dim3(34), dim3(256), 0, stream,
                     mu_k, Psi, nu, kap, mask, BG, c0o, nact, idxb);
  hipLaunchKernelGGL(main_kernel, dim3(BT_TOTAL / BT_BLK), dim3(256), 0, stream,
                     mu_t, var_t, F_t, BG, c0o, nact, idxb, outp);
}